// Round 5
// baseline (454.864 us; speedup 1.0000x reference)
//
#include <hip/hip_runtime.h>
#include <hip/hip_bf16.h>
#include <cmath>
#include <cstdint>

// ---------------------------------------------------------------------------
// QuantumTransformerBlock. Inputs f32, output f32 (reference dtypes).
// B=2,S=2048,E=1024,H=16,D=64,F=1024. M=4096,K=N=1024.
// Internals: bf16 MFMA GEMMs (m97 structure) + MFMA flash attention.
// Round-3/4 identical-absmax evidence validated this pipeline's math; the
// only fix vs round 3 is f32 in/out at the boundaries.
// Workspace: 34 MB + d_out (16 MB) as scratch.
// ---------------------------------------------------------------------------

typedef __bf16 bf16_t;
typedef __bf16 bf16x8 __attribute__((ext_vector_type(8)));
typedef float f32x4 __attribute__((ext_vector_type(4)));
typedef unsigned short u16x4 __attribute__((ext_vector_type(4)));

#define DEV_INLINE __device__ __forceinline__

DEV_INLINE void gload16(const void* g, void* lds) {
  __builtin_amdgcn_global_load_lds(
      (const __attribute__((address_space(1))) unsigned int*)g,
      (__attribute__((address_space(3))) unsigned int*)lds, 16, 0, 0);
}

DEV_INLINE unsigned short bf16_bits(float f) {
  bf16_t b = (bf16_t)f;
  return __builtin_bit_cast(unsigned short, b);
}

// ---------------------------------------------------------------------------
// x (f32, 4M elems) -> bf16
// ---------------------------------------------------------------------------
__global__ __launch_bounds__(256) void convx_kernel(const float* __restrict__ src,
                                                    bf16_t* __restrict__ dst) {
  const size_t i0 = ((size_t)blockIdx.x * 256 + threadIdx.x) * 8;
  bf16x8 v;
#pragma unroll
  for (int j = 0; j < 8; ++j) v[j] = (bf16_t)src[i0 + j];
  *(bf16x8*)(dst + i0) = v;
}

// ---------------------------------------------------------------------------
// transpose+convert 1024x1024: dst[n][k] = (bf16)src[k][n], src f32
// ---------------------------------------------------------------------------
__global__ __launch_bounds__(256) void tconv_kernel(const float* __restrict__ src,
                                                    bf16_t* __restrict__ dst) {
  __shared__ bf16_t t[32][33];
  const int bx = blockIdx.x * 32, by = blockIdx.y * 32;
  const int tx = threadIdx.x & 31, ty = threadIdx.x >> 5;
#pragma unroll
  for (int i = 0; i < 4; ++i) {
    t[ty + i * 8][tx] = (bf16_t)src[(size_t)(by + ty + i * 8) * 1024 + bx + tx];
  }
  __syncthreads();
#pragma unroll
  for (int i = 0; i < 4; ++i) {
    dst[(size_t)(bx + ty + i * 8) * 1024 + by + tx] = t[tx][ty + i * 8];
  }
}

// ---------------------------------------------------------------------------
// GEMM C[M,N] = A[M,K] * Bt[N,K]^T, BM=BN=128, BK=64, m97 structure.
// EPI_QK: o0[bh][s][d] bf16      EPI_VT: o0[bh][d][s] bf16
// EPI_WO: of32 = acc + auxf(x)               (res, f32)
// EPI_W1: ob16 = wsig*auxb + (1-wsig)*relu(acc+bias)   (h, bf16)
// EPI_W2: of32 = acc + bias + auxb(x1)       (res2, f32)
// ---------------------------------------------------------------------------
enum { EPI_QK = 0, EPI_VT = 1, EPI_WO = 2, EPI_W1 = 3, EPI_W2 = 4 };

template <int EPI>
__global__ __launch_bounds__(256) void gemm_bt_kernel(
    const bf16_t* __restrict__ A, const bf16_t* __restrict__ Bt,
    void* __restrict__ o0, const float* __restrict__ auxf,
    const bf16_t* __restrict__ auxb, const float* __restrict__ bias,
    const float* __restrict__ scal) {
  constexpr int K = 1024, BM = 128, BN = 128, BK = 64;
  __shared__ __align__(16) bf16_t As[BM * BK];
  __shared__ __align__(16) bf16_t Bs[BN * BK];

  const int tid = threadIdx.x;
  const int w = tid >> 6, lane = tid & 63;
  const int quad = lane >> 4, tc = lane & 15;
  const int m0 = blockIdx.y * BM, n0 = blockIdx.x * BN;
  const int wm = (w >> 1) * 64, wn = (w & 1) * 64;
  const int srow = lane >> 3, scol = (lane & 7) * 8;

  f32x4 acc[4][4] = {};

  const bf16_t* Ab = A + (size_t)m0 * K;
  const bf16_t* Bb = Bt + (size_t)n0 * K;

  for (int k0 = 0; k0 < K; k0 += BK) {
    __syncthreads();
#pragma unroll
    for (int it = 0; it < 4; ++it) {
      const int rbase = w * 32 + it * 8;
      gload16(Ab + (size_t)(rbase + srow) * K + k0 + scol, &As[rbase * BK]);
      gload16(Bb + (size_t)(rbase + srow) * K + k0 + scol, &Bs[rbase * BK]);
    }
    __syncthreads();
#pragma unroll
    for (int ks = 0; ks < 2; ++ks) {
      bf16x8 af[4], bfv[4];
#pragma unroll
      for (int i = 0; i < 4; ++i)
        af[i] = *(const bf16x8*)&As[(wm + i * 16 + tc) * BK + ks * 32 + quad * 8];
#pragma unroll
      for (int j = 0; j < 4; ++j)
        bfv[j] = *(const bf16x8*)&Bs[(wn + j * 16 + tc) * BK + ks * 32 + quad * 8];
#pragma unroll
      for (int i = 0; i < 4; ++i)
#pragma unroll
        for (int j = 0; j < 4; ++j)
          acc[i][j] = __builtin_amdgcn_mfma_f32_16x16x32_bf16(af[i], bfv[j],
                                                              acc[i][j], 0, 0, 0);
    }
  }

  float wsig = 0.f;
  if (EPI == EPI_W1) wsig = 1.f / (1.f + __expf(-scal[0]));

#pragma unroll
  for (int i = 0; i < 4; ++i) {
#pragma unroll
    for (int j = 0; j < 4; ++j) {
      const int row0 = m0 + wm + i * 16 + quad * 4;
      const int col = n0 + wn + j * 16 + tc;
      if (EPI == EPI_QK) {
        const int hh = col >> 6, d = col & 63;
#pragma unroll
        for (int r = 0; r < 4; ++r) {
          const int row = row0 + r;
          const int b = row >> 11, s = row & 2047;
          ((bf16_t*)o0)[((size_t)(b * 16 + hh) * 2048 + s) * 64 + d] =
              (bf16_t)acc[i][j][r];
        }
      } else if (EPI == EPI_VT) {
        const int hh = col >> 6, d = col & 63;
        const int b = row0 >> 11, s0 = row0 & 2047;
        u16x4 pk;
#pragma unroll
        for (int r = 0; r < 4; ++r) pk[r] = bf16_bits(acc[i][j][r]);
        *(u16x4*)((bf16_t*)o0 + ((size_t)(b * 16 + hh) * 64 + d) * 2048 + s0) = pk;
      } else if (EPI == EPI_WO) {
#pragma unroll
        for (int r = 0; r < 4; ++r) {
          const int row = row0 + r;
          ((float*)o0)[(size_t)row * 1024 + col] =
              acc[i][j][r] + auxf[(size_t)row * 1024 + col];
        }
      } else if (EPI == EPI_W1) {
#pragma unroll
        for (int r = 0; r < 4; ++r) {
          const int row = row0 + r;
          float c = fmaxf(acc[i][j][r] + bias[col], 0.f);
          const float qv = (float)auxb[(size_t)row * 1024 + col];
          ((bf16_t*)o0)[(size_t)row * 1024 + col] =
              (bf16_t)(wsig * qv + (1.f - wsig) * c);
        }
      } else {  // EPI_W2
#pragma unroll
        for (int r = 0; r < 4; ++r) {
          const int row = row0 + r;
          ((float*)o0)[(size_t)row * 1024 + col] =
              acc[i][j][r] + bias[col] + (float)auxb[(size_t)row * 1024 + col];
        }
      }
    }
  }
}

// ---------------------------------------------------------------------------
// Flash attention per (bh, q-tile of 64). MFMA 16x16x32, explicit staging.
// ---------------------------------------------------------------------------
__global__ __launch_bounds__(256) void attn_kernel(
    const bf16_t* __restrict__ q, const bf16_t* __restrict__ k,
    const bf16_t* __restrict__ vT, const float* __restrict__ aqw,
    bf16_t* __restrict__ out) {
  constexpr int S = 2048, KT = 64;
  __shared__ __align__(16) bf16_t Ks[64 * 64];
  __shared__ __align__(16) bf16_t Vs[64 * 64];
  __shared__ __align__(16) bf16_t Ps[4 * 16 * 64];
  __shared__ __align__(16) float Ql[64 * 64];
  __shared__ float segp[64][4];

  const int tid = threadIdx.x, w = tid >> 6, lane = tid & 63;
  const int quad = lane >> 4, tc = lane & 15;
  const int bh = blockIdx.y, q0 = blockIdx.x * 64;
  const bf16_t* qg = q + ((size_t)bh * S + q0) * 64;
  const bf16_t* kg = k + (size_t)bh * S * 64;
  const bf16_t* vg = vT + (size_t)bh * 64 * S;

  {
    const int rr = tid >> 2, ss = tid & 3;
    const bf16_t* qr = qg + rr * 64 + ss * 16;
    float c[16], p = 1.f;
#pragma unroll
    for (int j2 = 0; j2 < 16; ++j2) {
      c[j2] = __cosf((float)qr[j2]);
      p *= c[j2];
    }
    segp[rr][ss] = p;
    __syncthreads();
    float pre = 1.f;
    for (int u = 0; u < ss; ++u) pre *= segp[rr][u];
#pragma unroll
    for (int j2 = 0; j2 < 16; ++j2) {
      pre *= c[j2];
      Ql[rr * 64 + ss * 16 + j2] = pre;
    }
  }

  bf16x8 aq[2];
  {
    const int qrow = w * 16 + tc;
#pragma unroll
    for (int ks = 0; ks < 2; ++ks) {
      bf16x8 t = *(const bf16x8*)(qg + qrow * 64 + ks * 32 + quad * 8);
#pragma unroll
      for (int e = 0; e < 8; ++e) t[e] = (bf16_t)((float)t[e] * 0.125f);
      aq[ks] = t;
    }
  }

  float mrow[4] = {-1e30f, -1e30f, -1e30f, -1e30f};
  float lrow[4] = {0.f, 0.f, 0.f, 0.f};
  f32x4 o[4] = {};

  const int strow = tid >> 2, stcol = (tid & 3) * 16;

  for (int kt = 0; kt < S; kt += KT) {
    __syncthreads();
    {
      bf16x8 k0v = *(const bf16x8*)(kg + (size_t)(kt + strow) * 64 + stcol);
      bf16x8 k1v = *(const bf16x8*)(kg + (size_t)(kt + strow) * 64 + stcol + 8);
      bf16x8 v0v = *(const bf16x8*)(vg + (size_t)strow * S + kt + stcol);
      bf16x8 v1v = *(const bf16x8*)(vg + (size_t)strow * S + kt + stcol + 8);
      *(bf16x8*)&Ks[strow * 64 + stcol] = k0v;
      *(bf16x8*)&Ks[strow * 64 + stcol + 8] = k1v;
      *(bf16x8*)&Vs[strow * 64 + stcol] = v0v;
      *(bf16x8*)&Vs[strow * 64 + stcol + 8] = v1v;
    }
    __syncthreads();

    f32x4 sf[4] = {};
#pragma unroll
    for (int ks = 0; ks < 2; ++ks) {
#pragma unroll
      for (int nt = 0; nt < 4; ++nt) {
        bf16x8 bk = *(const bf16x8*)&Ks[(nt * 16 + tc) * 64 + ks * 32 + quad * 8];
        sf[nt] = __builtin_amdgcn_mfma_f32_16x16x32_bf16(aq[ks], bk, sf[nt], 0, 0, 0);
      }
    }

    float mnew[4], psum[4];
#pragma unroll
    for (int r = 0; r < 4; ++r) {
      float mx = fmaxf(fmaxf(sf[0][r], sf[1][r]), fmaxf(sf[2][r], sf[3][r]));
#pragma unroll
      for (int off = 8; off >= 1; off >>= 1) mx = fmaxf(mx, __shfl_xor(mx, off, 64));
      mnew[r] = fmaxf(mrow[r], mx);
      psum[r] = 0.f;
    }
#pragma unroll
    for (int nt = 0; nt < 4; ++nt) {
#pragma unroll
      for (int r = 0; r < 4; ++r) {
        const float p = __expf(sf[nt][r] - mnew[r]);
        psum[r] += p;
        Ps[w * 1024 + (quad * 4 + r) * 64 + nt * 16 + tc] = (bf16_t)p;
      }
    }
#pragma unroll
    for (int r = 0; r < 4; ++r) {
#pragma unroll
      for (int off = 8; off >= 1; off >>= 1) psum[r] += __shfl_xor(psum[r], off, 64);
      const float alpha = __expf(mrow[r] - mnew[r]);
      lrow[r] = lrow[r] * alpha + psum[r];
      mrow[r] = mnew[r];
#pragma unroll
      for (int j = 0; j < 4; ++j) o[j][r] *= alpha;
    }
    __syncthreads();

#pragma unroll
    for (int ks = 0; ks < 2; ++ks) {
      bf16x8 ap = *(const bf16x8*)&Ps[w * 1024 + tc * 64 + ks * 32 + quad * 8];
#pragma unroll
      for (int j = 0; j < 4; ++j) {
        bf16x8 bv = *(const bf16x8*)&Vs[(j * 16 + tc) * 64 + ks * 32 + quad * 8];
        o[j] = __builtin_amdgcn_mfma_f32_16x16x32_bf16(ap, bv, o[j], 0, 0, 0);
      }
    }
  }

  const float wsig = 1.f / (1.f + __expf(-aqw[0]));
  const int b = bh >> 4, h = bh & 15;
#pragma unroll
  for (int j = 0; j < 4; ++j) {
#pragma unroll
    for (int r = 0; r < 4; ++r) {
      const int lr = quad * 4 + r;
      const int sg = q0 + w * 16 + lr;
      const int d = j * 16 + tc;
      const float cl = o[j][r] / lrow[r];
      const float qv = Ql[(w * 16 + lr) * 64 + d];
      out[((size_t)(b * 2048 + sg)) * 1024 + h * 64 + d] =
          (bf16_t)(wsig * qv + (1.f - wsig) * cl);
    }
  }
}

// ---------------------------------------------------------------------------
// LayerNorm row of 1024: f32 in, f32 gain/beta, OT out (bf16 or f32)
// ---------------------------------------------------------------------------
template <typename OT>
__global__ __launch_bounds__(256) void ln_kernel(
    const float* __restrict__ res, const float* __restrict__ g,
    const float* __restrict__ bta, OT* __restrict__ out) {
  const int row = blockIdx.x;
  const float* r = res + (size_t)row * 1024;
  const int tid = threadIdx.x, w = tid >> 6, lane = tid & 63;
  float v[4], s = 0.f, sq = 0.f;
#pragma unroll
  for (int i = 0; i < 4; ++i) {
    v[i] = r[tid + i * 256];
    s += v[i];
    sq += v[i] * v[i];
  }
#pragma unroll
  for (int off = 32; off >= 1; off >>= 1) {
    s += __shfl_xor(s, off, 64);
    sq += __shfl_xor(sq, off, 64);
  }
  __shared__ float rs[4], rq[4];
  if (lane == 0) {
    rs[w] = s;
    rq[w] = sq;
  }
  __syncthreads();
  s = rs[0] + rs[1] + rs[2] + rs[3];
  sq = rq[0] + rq[1] + rq[2] + rq[3];
  const float mean = s * (1.f / 1024.f);
  const float var = fmaxf(sq * (1.f / 1024.f) - mean * mean, 0.f);
  const float rstd = rsqrtf(var + 1e-5f);
#pragma unroll
  for (int i = 0; i < 4; ++i) {
    const int e = tid + i * 256;
    out[(size_t)row * 1024 + e] = (OT)((v[i] - mean) * rstd * g[e] + bta[e]);
  }
}

// ---------------------------------------------------------------------------
// Row cumprod of cos over 1024; one wave per row.
// ---------------------------------------------------------------------------
__global__ __launch_bounds__(256) void scan_kernel(
    const bf16_t* __restrict__ x1, bf16_t* __restrict__ q2) {
  const int row = blockIdx.x * 4 + (threadIdx.x >> 6);
  const int lane = threadIdx.x & 63;
  const bf16_t* xr = x1 + (size_t)row * 1024 + lane * 16;
  float c[16], p = 1.f;
#pragma unroll
  for (int j = 0; j < 16; ++j) {
    c[j] = __cosf((float)xr[j]);
    p *= c[j];
  }
  float ip = p;
#pragma unroll
  for (int off = 1; off < 64; off <<= 1) {
    const float t = __shfl_up(ip, off, 64);
    if (lane >= off) ip *= t;
  }
  float run = __shfl_up(ip, 1, 64);
  if (lane == 0) run = 1.f;
  bf16_t* qr = q2 + (size_t)row * 1024 + lane * 16;
#pragma unroll
  for (int j = 0; j < 16; ++j) {
    run *= c[j];
    qr[j] = (bf16_t)run;
  }
}

// ---------------------------------------------------------------------------
extern "C" void kernel_launch(void* const* d_in, const int* in_sizes, int n_in,
                              void* d_out, int out_size, void* d_ws,
                              size_t ws_size, hipStream_t stream) {
  (void)in_sizes;
  (void)n_in;
  (void)out_size;
  (void)ws_size;
  const float* x = (const float*)d_in[0];
  const float* wq = (const float*)d_in[2];
  const float* wk = (const float*)d_in[3];
  const float* wv = (const float*)d_in[4];
  const float* wo = (const float*)d_in[5];
  const float* attn_qw = (const float*)d_in[7];
  const float* w1 = (const float*)d_in[8];
  const float* b1 = (const float*)d_in[9];
  const float* w2 = (const float*)d_in[10];
  const float* b2 = (const float*)d_in[11];
  const float* ffn_qw = (const float*)d_in[13];
  const float* ln1_g = (const float*)d_in[14];
  const float* ln1_b = (const float*)d_in[15];
  const float* ln2_g = (const float*)d_in[16];
  const float* ln2_b = (const float*)d_in[17];

  char* ws = (char*)d_ws;
  bf16_t* wT = (bf16_t*)(ws + 0);              // [0,2M)   per-weight transpose
  bf16_t* xc = (bf16_t*)(ws + 2097152);        // [2M,10M) x as bf16
  bf16_t* qb = (bf16_t*)(ws + 10485760);       // [10M,18M)
  bf16_t* kb = (bf16_t*)(ws + 18874368);       // [18M,26M)
  bf16_t* vTb = (bf16_t*)(ws + 27262976);      // [26M,34M)
  float* res = (float*)(ws + 10485760);        // [10M,26M) overlays q+k
  bf16_t* x1 = (bf16_t*)(ws + 27262976);       // [26M,34M) overlays vT
  bf16_t* q2 = (bf16_t*)(ws + 2097152);        // [2M,10M)  overlays xc
  float* res2 = (float*)(ws + 10485760);       // [10M,26M)
  bf16_t* aout = (bf16_t*)d_out;               // d_out scratch (dies after WO)
  bf16_t* hbuf = (bf16_t*)d_out;               // d_out scratch (dies after ln2)

  const dim3 tb(256);
  const dim3 gT(32, 32);
  const dim3 gG(8, 32);

  convx_kernel<<<2048, tb, 0, stream>>>(x, xc);

  tconv_kernel<<<gT, tb, 0, stream>>>(wq, wT);
  gemm_bt_kernel<EPI_QK><<<gG, tb, 0, stream>>>(xc, wT, qb, nullptr, nullptr, nullptr, nullptr);
  tconv_kernel<<<gT, tb, 0, stream>>>(wk, wT);
  gemm_bt_kernel<EPI_QK><<<gG, tb, 0, stream>>>(xc, wT, kb, nullptr, nullptr, nullptr, nullptr);
  tconv_kernel<<<gT, tb, 0, stream>>>(wv, wT);
  gemm_bt_kernel<EPI_VT><<<gG, tb, 0, stream>>>(xc, wT, vTb, nullptr, nullptr, nullptr, nullptr);

  attn_kernel<<<dim3(32, 32), tb, 0, stream>>>(qb, kb, vTb, attn_qw, aout);

  tconv_kernel<<<gT, tb, 0, stream>>>(wo, wT);
  gemm_bt_kernel<EPI_WO><<<gG, tb, 0, stream>>>(aout, wT, res, x, nullptr, nullptr, nullptr);

  ln_kernel<bf16_t><<<4096, tb, 0, stream>>>(res, ln1_g, ln1_b, x1);

  scan_kernel<<<1024, tb, 0, stream>>>(x1, q2);

  tconv_kernel<<<gT, tb, 0, stream>>>(w1, wT);
  gemm_bt_kernel<EPI_W1><<<gG, tb, 0, stream>>>(x1, wT, hbuf, nullptr, q2, b1, ffn_qw);

  tconv_kernel<<<gT, tb, 0, stream>>>(w2, wT);
  gemm_bt_kernel<EPI_W2><<<gG, tb, 0, stream>>>(hbuf, wT, res2, nullptr, x1, b2, nullptr);

  ln_kernel<float><<<4096, tb, 0, stream>>>(res2, ln2_g, ln2_b, (float*)d_out);
}

// Round 6
// 333.726 us; speedup vs baseline: 1.3630x; 1.3630x over previous
//
#include <hip/hip_runtime.h>
#include <hip/hip_bf16.h>
#include <cmath>
#include <cstdint>

// ---------------------------------------------------------------------------
// QuantumTransformerBlock. Inputs f32, output f32. Internals bf16 MFMA.
// B=2,S=2048,E=1024,H=16,D=64,F=1024. M=4096,K=1024.
// R6: attn LDS pad 72 (kill 3.7e7 bank conflicts), no-max softmax, S^T MFMA
//     (vector Ps writes, waitcnt instead of 3rd barrier), Ql bf16 (4 blk/CU),
//     fused QKV GEMM (N=3072), merged qkv transpose. ws = 32 MB + d_out.
// ---------------------------------------------------------------------------

typedef __bf16 bf16_t;
typedef __bf16 bf16x8 __attribute__((ext_vector_type(8)));
typedef float f32x4 __attribute__((ext_vector_type(4)));
typedef unsigned short u16x4 __attribute__((ext_vector_type(4)));

#define DEV_INLINE __device__ __forceinline__
#define MB 1048576

DEV_INLINE void gload16(const void* g, void* lds) {
  __builtin_amdgcn_global_load_lds(
      (const __attribute__((address_space(1))) unsigned int*)g,
      (__attribute__((address_space(3))) unsigned int*)lds, 16, 0, 0);
}

DEV_INLINE unsigned short bf16_bits(float f) {
  bf16_t b = (bf16_t)f;
  return __builtin_bit_cast(unsigned short, b);
}

// ---------------------------------------------------------------------------
// x (f32, 4M elems) -> bf16
// ---------------------------------------------------------------------------
__global__ __launch_bounds__(256) void convx_kernel(const float* __restrict__ src,
                                                    bf16_t* __restrict__ dst) {
  const size_t i0 = ((size_t)blockIdx.x * 256 + threadIdx.x) * 8;
  bf16x8 v;
#pragma unroll
  for (int j = 0; j < 8; ++j) v[j] = (bf16_t)src[i0 + j];
  *(bf16x8*)(dst + i0) = v;
}

// ---------------------------------------------------------------------------
// transpose+convert 1024x1024 f32 -> bf16: dst[n][k] = src[k][n]
// ---------------------------------------------------------------------------
__global__ __launch_bounds__(256) void tconv_kernel(const float* __restrict__ src,
                                                    bf16_t* __restrict__ dst) {
  __shared__ bf16_t t[32][33];
  const int bx = blockIdx.x * 32, by = blockIdx.y * 32;
  const int tx = threadIdx.x & 31, ty = threadIdx.x >> 5;
#pragma unroll
  for (int i = 0; i < 4; ++i)
    t[ty + i * 8][tx] = (bf16_t)src[(size_t)(by + ty + i * 8) * 1024 + bx + tx];
  __syncthreads();
#pragma unroll
  for (int i = 0; i < 4; ++i)
    dst[(size_t)(bx + ty + i * 8) * 1024 + by + tx] = t[tx][ty + i * 8];
}

// merged wq|wk|wv -> wqkvT[3072][1024]
__global__ __launch_bounds__(256) void tconv3_kernel(const float* __restrict__ wq,
                                                     const float* __restrict__ wk,
                                                     const float* __restrict__ wv,
                                                     bf16_t* __restrict__ dst) {
  __shared__ bf16_t t[32][33];
  const int mi = blockIdx.x >> 5;
  const float* src = (mi == 0) ? wq : (mi == 1) ? wk : wv;
  const int bx = (blockIdx.x & 31) * 32, by = blockIdx.y * 32;
  const int tx = threadIdx.x & 31, ty = threadIdx.x >> 5;
#pragma unroll
  for (int i = 0; i < 4; ++i)
    t[ty + i * 8][tx] = (bf16_t)src[(size_t)(by + ty + i * 8) * 1024 + bx + tx];
  __syncthreads();
#pragma unroll
  for (int i = 0; i < 4; ++i)
    dst[(size_t)(mi * 1024 + bx + ty + i * 8) * 1024 + by + tx] = t[tx][ty + i * 8];
}

// ---------------------------------------------------------------------------
// GEMM C[M,N] = A[M,K] * Bt[N,K]^T, BM=BN=128, BK=64, m97 structure.
// ---------------------------------------------------------------------------
enum { EPI_QKV = 0, EPI_WO = 2, EPI_W1 = 3, EPI_W2 = 4 };

template <int EPI>
__global__ __launch_bounds__(256) void gemm_bt_kernel(
    const bf16_t* __restrict__ A, const bf16_t* __restrict__ Bt,
    void* __restrict__ o0, void* __restrict__ o1, void* __restrict__ o2,
    const float* __restrict__ auxf, const bf16_t* __restrict__ auxb,
    const float* __restrict__ bias, const float* __restrict__ scal) {
  constexpr int K = 1024, BM = 128, BK = 64;
  __shared__ __align__(16) bf16_t As[BM * BK];
  __shared__ __align__(16) bf16_t Bs[BM * BK];

  const int tid = threadIdx.x;
  const int w = tid >> 6, lane = tid & 63;
  const int quad = lane >> 4, tc = lane & 15;
  const int m0 = blockIdx.y * BM, n0 = blockIdx.x * BM;
  const int wm = (w >> 1) * 64, wn = (w & 1) * 64;
  const int srow = lane >> 3, scol = (lane & 7) * 8;

  f32x4 acc[4][4] = {};

  const bf16_t* Ab = A + (size_t)m0 * K;
  const bf16_t* Bb = Bt + (size_t)n0 * K;

  for (int k0 = 0; k0 < K; k0 += BK) {
    __syncthreads();
#pragma unroll
    for (int it = 0; it < 4; ++it) {
      const int rbase = w * 32 + it * 8;
      gload16(Ab + (size_t)(rbase + srow) * K + k0 + scol, &As[rbase * BK]);
      gload16(Bb + (size_t)(rbase + srow) * K + k0 + scol, &Bs[rbase * BK]);
    }
    __syncthreads();
#pragma unroll
    for (int ks = 0; ks < 2; ++ks) {
      bf16x8 af[4], bfv[4];
#pragma unroll
      for (int i = 0; i < 4; ++i)
        af[i] = *(const bf16x8*)&As[(wm + i * 16 + tc) * BK + ks * 32 + quad * 8];
#pragma unroll
      for (int j = 0; j < 4; ++j)
        bfv[j] = *(const bf16x8*)&Bs[(wn + j * 16 + tc) * BK + ks * 32 + quad * 8];
#pragma unroll
      for (int i = 0; i < 4; ++i)
#pragma unroll
        for (int j = 0; j < 4; ++j)
          acc[i][j] = __builtin_amdgcn_mfma_f32_16x16x32_bf16(af[i], bfv[j],
                                                              acc[i][j], 0, 0, 0);
    }
  }

  float wsig = 0.f;
  if (EPI == EPI_W1) wsig = 1.f / (1.f + __expf(-scal[0]));

#pragma unroll
  for (int i = 0; i < 4; ++i) {
#pragma unroll
    for (int j = 0; j < 4; ++j) {
      const int row0 = m0 + wm + i * 16 + quad * 4;
      const int col = n0 + wn + j * 16 + tc;
      if (EPI == EPI_QKV) {
        const int part = col >> 10, e = col & 1023, hh = e >> 6, d = e & 63;
        if (part == 2) {
          const int b = row0 >> 11, s0 = row0 & 2047;
          u16x4 pk;
#pragma unroll
          for (int r = 0; r < 4; ++r) pk[r] = bf16_bits(acc[i][j][r]);
          *(u16x4*)((bf16_t*)o2 + ((size_t)((b * 16 + hh) * 64 + d)) * 2048 + s0) = pk;
        } else {
          bf16_t* dst = part ? (bf16_t*)o1 : (bf16_t*)o0;
#pragma unroll
          for (int r = 0; r < 4; ++r) {
            const int row = row0 + r;
            const int b = row >> 11, s = row & 2047;
            dst[((size_t)(b * 16 + hh) * 2048 + s) * 64 + d] = (bf16_t)acc[i][j][r];
          }
        }
      } else if (EPI == EPI_WO) {
#pragma unroll
        for (int r = 0; r < 4; ++r) {
          const int row = row0 + r;
          ((float*)o0)[(size_t)row * 1024 + col] =
              acc[i][j][r] + auxf[(size_t)row * 1024 + col];
        }
      } else if (EPI == EPI_W1) {
#pragma unroll
        for (int r = 0; r < 4; ++r) {
          const int row = row0 + r;
          float c = fmaxf(acc[i][j][r] + bias[col], 0.f);
          const float qv = (float)auxb[(size_t)row * 1024 + col];
          ((bf16_t*)o0)[(size_t)row * 1024 + col] =
              (bf16_t)(wsig * qv + (1.f - wsig) * c);
        }
      } else {  // EPI_W2
#pragma unroll
        for (int r = 0; r < 4; ++r) {
          const int row = row0 + r;
          ((float*)o0)[(size_t)row * 1024 + col] =
              acc[i][j][r] + bias[col] + (float)auxb[(size_t)row * 1024 + col];
        }
      }
    }
  }
}

// ---------------------------------------------------------------------------
// Flash attention per (bh, q-tile 64). Padded LDS (stride 72), no-max softmax,
// S^T = K*Q^T MFMA (vector Ps writes), wave-local Ps (waitcnt, no 3rd barrier).
// ---------------------------------------------------------------------------
__global__ __launch_bounds__(256) void attn_kernel(
    const bf16_t* __restrict__ q, const bf16_t* __restrict__ k,
    const bf16_t* __restrict__ vT, const float* __restrict__ aqw,
    bf16_t* __restrict__ out) {
  constexpr int S = 2048, LDK = 72;
  __shared__ __align__(16) bf16_t Ks[64 * LDK];
  __shared__ __align__(16) bf16_t Vs[64 * LDK];
  __shared__ __align__(16) bf16_t Ps[4 * 16 * LDK];
  __shared__ bf16_t Ql[64 * 64];
  __shared__ float segp[64][4];

  const int tid = threadIdx.x, w = tid >> 6, lane = tid & 63;
  const int quad = lane >> 4, tc = lane & 15;
  const int bh = blockIdx.y, q0 = blockIdx.x * 64;
  const bf16_t* qg = q + ((size_t)bh * S + q0) * 64;
  const bf16_t* kg = k + (size_t)bh * S * 64;
  const bf16_t* vg = vT + (size_t)bh * 64 * S;

  // quantum: cumprod(cos(q)) per row, 4 threads/row, Ql bf16
  {
    const int rr = tid >> 2, ss = tid & 3;
    const bf16_t* qr = qg + rr * 64 + ss * 16;
    float c[16], p = 1.f;
#pragma unroll
    for (int j2 = 0; j2 < 16; ++j2) {
      c[j2] = __cosf((float)qr[j2]);
      p *= c[j2];
    }
    segp[rr][ss] = p;
    __syncthreads();
    float pre = 1.f;
    for (int u = 0; u < ss; ++u) pre *= segp[rr][u];
#pragma unroll
    for (int j2 = 0; j2 < 16; ++j2) {
      pre *= c[j2];
      Ql[rr * 64 + ss * 16 + j2] = (bf16_t)pre;
    }
  }

  // Q fragment (B-operand of S^T = K Q^T), pre-scaled by 1/8
  bf16x8 aq[2];
  {
    const int qrow = w * 16 + tc;
#pragma unroll
    for (int ks = 0; ks < 2; ++ks) {
      bf16x8 t = *(const bf16x8*)(qg + qrow * 64 + ks * 32 + quad * 8);
#pragma unroll
      for (int e = 0; e < 8; ++e) t[e] = (bf16_t)((float)t[e] * 0.125f);
      aq[ks] = t;
    }
  }

  float lacc = 0.f;
  f32x4 o[4] = {};
  bf16_t* Pw = &Ps[w * 16 * LDK];

  const int strow = tid >> 2, stcol = (tid & 3) * 16;

  for (int kt = 0; kt < S; kt += 64) {
    __syncthreads();  // WAR on Ks/Vs
    {
      bf16x8 k0v = *(const bf16x8*)(kg + (size_t)(kt + strow) * 64 + stcol);
      bf16x8 k1v = *(const bf16x8*)(kg + (size_t)(kt + strow) * 64 + stcol + 8);
      bf16x8 v0v = *(const bf16x8*)(vg + (size_t)strow * S + kt + stcol);
      bf16x8 v1v = *(const bf16x8*)(vg + (size_t)strow * S + kt + stcol + 8);
      *(bf16x8*)&Ks[strow * LDK + stcol] = k0v;
      *(bf16x8*)&Ks[strow * LDK + stcol + 8] = k1v;
      *(bf16x8*)&Vs[strow * LDK + stcol] = v0v;
      *(bf16x8*)&Vs[strow * LDK + stcol + 8] = v1v;
    }
    __syncthreads();

    // S^T tile: rows = keys (4 m-tiles), cols = 16 q-rows
    f32x4 sf[4] = {};
#pragma unroll
    for (int ks = 0; ks < 2; ++ks) {
#pragma unroll
      for (int nt = 0; nt < 4; ++nt) {
        bf16x8 ak = *(const bf16x8*)&Ks[(nt * 16 + tc) * LDK + ks * 32 + quad * 8];
        sf[nt] = __builtin_amdgcn_mfma_f32_16x16x32_bf16(ak, aq[ks], sf[nt], 0, 0, 0);
      }
    }

    // p = exp(s) (scores tame: |s| <~ 3); keys contiguous per lane -> b64 write
#pragma unroll
    for (int nt = 0; nt < 4; ++nt) {
      u16x4 pk;
      float ps = 0.f;
#pragma unroll
      for (int r = 0; r < 4; ++r) {
        const float p = __expf(sf[nt][r]);
        ps += p;
        pk[r] = bf16_bits(p);
      }
      lacc += ps;
      *(u16x4*)&Pw[tc * LDK + nt * 16 + quad * 4] = pk;
    }
    // Ps is per-wave: wave-local LDS ordering is enough
    asm volatile("s_waitcnt lgkmcnt(0)" ::: "memory");

    // O += P V
#pragma unroll
    for (int ks = 0; ks < 2; ++ks) {
      bf16x8 ap = *(const bf16x8*)&Pw[tc * LDK + ks * 32 + quad * 8];
#pragma unroll
      for (int j = 0; j < 4; ++j) {
        bf16x8 bv = *(const bf16x8*)&Vs[(j * 16 + tc) * LDK + ks * 32 + quad * 8];
        o[j] = __builtin_amdgcn_mfma_f32_16x16x32_bf16(ap, bv, o[j], 0, 0, 0);
      }
    }
  }

  // l per q-row: lanes sharing tc hold disjoint key-partials
  lacc += __shfl_xor(lacc, 16, 64);
  lacc += __shfl_xor(lacc, 32, 64);

  const float wsig = 1.f / (1.f + __expf(-aqw[0]));
  const int b = bh >> 4, h = bh & 15;
#pragma unroll
  for (int r = 0; r < 4; ++r) {
    const int lr = quad * 4 + r;
    const float linv = 1.f / __shfl(lacc, lr, 64);
    const int sg = q0 + w * 16 + lr;
#pragma unroll
    for (int j = 0; j < 4; ++j) {
      const int d = j * 16 + tc;
      const float cl = o[j][r] * linv;
      const float qv = (float)Ql[(w * 16 + lr) * 64 + d];
      out[((size_t)(b * 2048 + sg)) * 1024 + h * 64 + d] =
          (bf16_t)(wsig * qv + (1.f - wsig) * cl);
    }
  }
}

// ---------------------------------------------------------------------------
// LayerNorm row of 1024: f32 in, OT out
// ---------------------------------------------------------------------------
template <typename OT>
__global__ __launch_bounds__(256) void ln_kernel(
    const float* __restrict__ res, const float* __restrict__ g,
    const float* __restrict__ bta, OT* __restrict__ out) {
  const int row = blockIdx.x;
  const float* r = res + (size_t)row * 1024;
  const int tid = threadIdx.x, w = tid >> 6, lane = tid & 63;
  float v[4], s = 0.f, sq = 0.f;
#pragma unroll
  for (int i = 0; i < 4; ++i) {
    v[i] = r[tid + i * 256];
    s += v[i];
    sq += v[i] * v[i];
  }
#pragma unroll
  for (int off = 32; off >= 1; off >>= 1) {
    s += __shfl_xor(s, off, 64);
    sq += __shfl_xor(sq, off, 64);
  }
  __shared__ float rs[4], rq[4];
  if (lane == 0) {
    rs[w] = s;
    rq[w] = sq;
  }
  __syncthreads();
  s = rs[0] + rs[1] + rs[2] + rs[3];
  sq = rq[0] + rq[1] + rq[2] + rq[3];
  const float mean = s * (1.f / 1024.f);
  const float var = fmaxf(sq * (1.f / 1024.f) - mean * mean, 0.f);
  const float rstd = rsqrtf(var + 1e-5f);
#pragma unroll
  for (int i = 0; i < 4; ++i) {
    const int e = tid + i * 256;
    out[(size_t)row * 1024 + e] = (OT)((v[i] - mean) * rstd * g[e] + bta[e]);
  }
}

// ---------------------------------------------------------------------------
// Row cumprod of cos over 1024; one wave per row.
// ---------------------------------------------------------------------------
__global__ __launch_bounds__(256) void scan_kernel(
    const bf16_t* __restrict__ x1, bf16_t* __restrict__ q2) {
  const int row = blockIdx.x * 4 + (threadIdx.x >> 6);
  const int lane = threadIdx.x & 63;
  const bf16_t* xr = x1 + (size_t)row * 1024 + lane * 16;
  float c[16], p = 1.f;
#pragma unroll
  for (int j = 0; j < 16; ++j) {
    c[j] = __cosf((float)xr[j]);
    p *= c[j];
  }
  float ip = p;
#pragma unroll
  for (int off = 1; off < 64; off <<= 1) {
    const float t = __shfl_up(ip, off, 64);
    if (lane >= off) ip *= t;
  }
  float run = __shfl_up(ip, 1, 64);
  if (lane == 0) run = 1.f;
  bf16_t* qr = q2 + (size_t)row * 1024 + lane * 16;
#pragma unroll
  for (int j = 0; j < 16; ++j) {
    run *= c[j];
    qr[j] = (bf16_t)run;
  }
}

// ---------------------------------------------------------------------------
extern "C" void kernel_launch(void* const* d_in, const int* in_sizes, int n_in,
                              void* d_out, int out_size, void* d_ws,
                              size_t ws_size, hipStream_t stream) {
  (void)in_sizes;
  (void)n_in;
  (void)out_size;
  (void)ws_size;
  const float* x = (const float*)d_in[0];
  const float* wq = (const float*)d_in[2];
  const float* wk = (const float*)d_in[3];
  const float* wv = (const float*)d_in[4];
  const float* wo = (const float*)d_in[5];
  const float* attn_qw = (const float*)d_in[7];
  const float* w1 = (const float*)d_in[8];
  const float* b1 = (const float*)d_in[9];
  const float* w2 = (const float*)d_in[10];
  const float* b2 = (const float*)d_in[11];
  const float* ffn_qw = (const float*)d_in[13];
  const float* ln1_g = (const float*)d_in[14];
  const float* ln1_b = (const float*)d_in[15];
  const float* ln2_g = (const float*)d_in[16];
  const float* ln2_b = (const float*)d_in[17];

  char* ws = (char*)d_ws;
  char* wsout = (char*)d_out;
  // ws (32 MB), lifetimes:
  bf16_t* wqkvT = (bf16_t*)(ws + 0);            // [0,6M)   dies after QKV
  bf16_t* xc = (bf16_t*)(ws + 6 * MB);          // [6,14M)  dies after QKV
  bf16_t* qb = (bf16_t*)(ws + 14 * MB);         // [14,22M) dies after attn
  bf16_t* kb = (bf16_t*)(ws + 22 * MB);         // [22,30M) dies after attn
  bf16_t* wT = (bf16_t*)(ws + 30 * MB);         // [30,32M) wo/w1/w2 serial
  float* res = (float*)(ws + 14 * MB);          // [14,30M) overlays qb+kb
  bf16_t* x1 = (bf16_t*)(ws + 0);               // [0,8M)   after WO
  float* res2 = (float*)(ws + 14 * MB);         // [14,30M)
  // d_out (16 MB) as scratch:
  bf16_t* vTb = (bf16_t*)(wsout + 0);           // [0,8M)   dies after attn
  bf16_t* aout = (bf16_t*)(wsout + 8 * MB);     // [8,16M)  dies after WO
  bf16_t* q2 = (bf16_t*)(wsout + 0);            // [0,8M)   after attn
  bf16_t* hbuf = (bf16_t*)(wsout + 8 * MB);     // [8,16M)  after WO

  const dim3 tb(256);
  const dim3 gT(32, 32);
  const dim3 gG(8, 32);

  convx_kernel<<<2048, tb, 0, stream>>>(x, xc);
  tconv3_kernel<<<dim3(96, 32), tb, 0, stream>>>(wq, wk, wv, wqkvT);

  gemm_bt_kernel<EPI_QKV><<<dim3(24, 32), tb, 0, stream>>>(
      xc, wqkvT, qb, kb, vTb, nullptr, nullptr, nullptr, nullptr);

  attn_kernel<<<dim3(32, 32), tb, 0, stream>>>(qb, kb, vTb, attn_qw, aout);

  tconv_kernel<<<gT, tb, 0, stream>>>(wo, wT);
  gemm_bt_kernel<EPI_WO><<<gG, tb, 0, stream>>>(
      aout, wT, res, nullptr, nullptr, x, nullptr, nullptr, nullptr);

  ln_kernel<bf16_t><<<4096, tb, 0, stream>>>(res, ln1_g, ln1_b, x1);

  scan_kernel<<<1024, tb, 0, stream>>>(x1, q2);

  tconv_kernel<<<gT, tb, 0, stream>>>(w1, wT);
  gemm_bt_kernel<EPI_W1><<<gG, tb, 0, stream>>>(
      x1, wT, hbuf, nullptr, nullptr, nullptr, q2, b1, ffn_qw);

  tconv_kernel<<<gT, tb, 0, stream>>>(w2, wT);
  gemm_bt_kernel<EPI_W2><<<gG, tb, 0, stream>>>(
      hbuf, wT, res2, nullptr, nullptr, nullptr, x1, b2, nullptr);

  ln_kernel<float><<<4096, tb, 0, stream>>>(res2, ln2_g, ln2_b, (float*)d_out);
}

// Round 7
// 308.970 us; speedup vs baseline: 1.4722x; 1.0801x over previous
//
#include <hip/hip_runtime.h>
#include <hip/hip_bf16.h>
#include <cmath>
#include <cstdint>

// ---------------------------------------------------------------------------
// QuantumTransformerBlock. Inputs f32, output f32. Internals bf16 MFMA.
// R7: Ql pad 72 (last conflicts), BM=64 GEMMs for W* (2 blk/CU), V^T computed
//     as wv^T x^T (coalesced stores), LN1+scan fused, merged transposes.
// ws <= 30 MB; d_out used as scratch.
// ---------------------------------------------------------------------------

typedef __bf16 bf16_t;
typedef __bf16 bf16x8 __attribute__((ext_vector_type(8)));
typedef float f32x4 __attribute__((ext_vector_type(4)));
typedef unsigned short u16x4 __attribute__((ext_vector_type(4)));

#define DEV_INLINE __device__ __forceinline__
#define MB 1048576

DEV_INLINE void gload16(const void* g, void* lds) {
  __builtin_amdgcn_global_load_lds(
      (const __attribute__((address_space(1))) unsigned int*)g,
      (__attribute__((address_space(3))) unsigned int*)lds, 16, 0, 0);
}

DEV_INLINE unsigned short bf16_bits(float f) {
  bf16_t b = (bf16_t)f;
  return __builtin_bit_cast(unsigned short, b);
}

// ---------------------------------------------------------------------------
// x (f32, 4M elems) -> bf16
// ---------------------------------------------------------------------------
__global__ __launch_bounds__(256) void convx_kernel(const float* __restrict__ src,
                                                    bf16_t* __restrict__ dst) {
  const size_t i0 = ((size_t)blockIdx.x * 256 + threadIdx.x) * 8;
  bf16x8 v;
#pragma unroll
  for (int j = 0; j < 8; ++j) v[j] = (bf16_t)src[i0 + j];
  *(bf16x8*)(dst + i0) = v;
}

// ---------------------------------------------------------------------------
// merged transpose+convert: 3x (1024x1024 f32) -> dst[3072][1024] bf16
// ---------------------------------------------------------------------------
__global__ __launch_bounds__(256) void tconv3_kernel(const float* __restrict__ w0,
                                                     const float* __restrict__ w1,
                                                     const float* __restrict__ w2,
                                                     bf16_t* __restrict__ dst) {
  __shared__ bf16_t t[32][33];
  const int mi = blockIdx.x >> 5;
  const float* src = (mi == 0) ? w0 : (mi == 1) ? w1 : w2;
  const int bx = (blockIdx.x & 31) * 32, by = blockIdx.y * 32;
  const int tx = threadIdx.x & 31, ty = threadIdx.x >> 5;
#pragma unroll
  for (int i = 0; i < 4; ++i)
    t[ty + i * 8][tx] = (bf16_t)src[(size_t)(by + ty + i * 8) * 1024 + bx + tx];
  __syncthreads();
#pragma unroll
  for (int i = 0; i < 4; ++i)
    dst[(size_t)(mi * 1024 + bx + ty + i * 8) * 1024 + by + tx] = t[tx][ty + i * 8];
}

// ---------------------------------------------------------------------------
// GEMM C[M,N] = A[M,K] * Bt[N,K]^T. BN=128, BK=64; BM = IM*32 (IM=4 -> 128,
// IM=2 -> 64). 256 thr = 4 waves (2x2), wave tile (IM*16) x 64.
// ---------------------------------------------------------------------------
enum { EPI_QK = 0, EPI_VT = 1, EPI_WO = 2, EPI_W1 = 3, EPI_W2 = 4 };

template <int EPI, int IM>
__global__ __launch_bounds__(256) void gemm_bt_kernel(
    const bf16_t* __restrict__ A, const bf16_t* __restrict__ Bt,
    void* __restrict__ o0, void* __restrict__ o1,
    const float* __restrict__ auxf, const bf16_t* __restrict__ auxb,
    const float* __restrict__ bias, const float* __restrict__ scal) {
  constexpr int K = 1024, BM = IM * 32, BK = 64;
  __shared__ __align__(16) bf16_t As[BM * BK];
  __shared__ __align__(16) bf16_t Bs[128 * BK];

  const int tid = threadIdx.x;
  const int w = tid >> 6, lane = tid & 63;
  const int quad = lane >> 4, tc = lane & 15;
  const int m0 = blockIdx.y * BM, n0 = blockIdx.x * 128;
  const int wm = (w >> 1) * (IM * 16), wn = (w & 1) * 64;
  const int srow = lane >> 3, scol = (lane & 7) * 8;

  f32x4 acc[IM][4] = {};

  const bf16_t* Ab = A + (size_t)m0 * K;
  const bf16_t* Bb = Bt + (size_t)n0 * K;

  for (int k0 = 0; k0 < K; k0 += BK) {
    __syncthreads();
#pragma unroll
    for (int it = 0; it < IM; ++it) {
      const int rbase = w * (IM * 8) + it * 8;
      gload16(Ab + (size_t)(rbase + srow) * K + k0 + scol, &As[rbase * BK]);
    }
#pragma unroll
    for (int it = 0; it < 4; ++it) {
      const int rbase = w * 32 + it * 8;
      gload16(Bb + (size_t)(rbase + srow) * K + k0 + scol, &Bs[rbase * BK]);
    }
    __syncthreads();
#pragma unroll
    for (int ks = 0; ks < 2; ++ks) {
      bf16x8 af[IM], bfv[4];
#pragma unroll
      for (int i = 0; i < IM; ++i)
        af[i] = *(const bf16x8*)&As[(wm + i * 16 + tc) * BK + ks * 32 + quad * 8];
#pragma unroll
      for (int j = 0; j < 4; ++j)
        bfv[j] = *(const bf16x8*)&Bs[(wn + j * 16 + tc) * BK + ks * 32 + quad * 8];
#pragma unroll
      for (int i = 0; i < IM; ++i)
#pragma unroll
        for (int j = 0; j < 4; ++j)
          acc[i][j] = __builtin_amdgcn_mfma_f32_16x16x32_bf16(af[i], bfv[j],
                                                              acc[i][j], 0, 0, 0);
    }
  }

  float wsig = 0.f;
  if (EPI == EPI_W1) wsig = 1.f / (1.f + __expf(-scal[0]));

#pragma unroll
  for (int i = 0; i < IM; ++i) {
#pragma unroll
    for (int j = 0; j < 4; ++j) {
      const int row0 = m0 + wm + i * 16 + quad * 4;
      const int col = n0 + wn + j * 16 + tc;
      if (EPI == EPI_QK) {
        // rows = s (4096), cols = 2*E: q then k. store [bh][s][d]
        const int part = col >> 10, e = col & 1023, hh = e >> 6, d = e & 63;
        bf16_t* dst = part ? (bf16_t*)o1 : (bf16_t*)o0;
#pragma unroll
        for (int r = 0; r < 4; ++r) {
          const int row = row0 + r;
          const int b = row >> 11, s = row & 2047;
          dst[((size_t)(b * 16 + hh) * 2048 + s) * 64 + d] = (bf16_t)acc[i][j][r];
        }
      } else if (EPI == EPI_VT) {
        // rows = e (1024), cols = s-global (4096). store [b*1024+e][s]
        const int b = col >> 11, s = col & 2047;
#pragma unroll
        for (int r = 0; r < 4; ++r) {
          ((bf16_t*)o0)[((size_t)(b * 1024 + row0 + r)) * 2048 + s] =
              (bf16_t)acc[i][j][r];
        }
      } else if (EPI == EPI_WO) {
#pragma unroll
        for (int r = 0; r < 4; ++r) {
          const int row = row0 + r;
          ((float*)o0)[(size_t)row * 1024 + col] =
              acc[i][j][r] + auxf[(size_t)row * 1024 + col];
        }
      } else if (EPI == EPI_W1) {
#pragma unroll
        for (int r = 0; r < 4; ++r) {
          const int row = row0 + r;
          float c = fmaxf(acc[i][j][r] + bias[col], 0.f);
          const float qv = (float)auxb[(size_t)row * 1024 + col];
          ((bf16_t*)o0)[(size_t)row * 1024 + col] =
              (bf16_t)(wsig * qv + (1.f - wsig) * c);
        }
      } else {  // EPI_W2
#pragma unroll
        for (int r = 0; r < 4; ++r) {
          const int row = row0 + r;
          ((float*)o0)[(size_t)row * 1024 + col] =
              acc[i][j][r] + bias[col] + (float)auxb[(size_t)row * 1024 + col];
        }
      }
    }
  }
}

// ---------------------------------------------------------------------------
// Flash attention per (bh, q-tile 64). All LDS strides 72 (conflict-free),
// no-max softmax, S^T = K*Q^T MFMA, wave-local Ps.
// ---------------------------------------------------------------------------
__global__ __launch_bounds__(256) void attn_kernel(
    const bf16_t* __restrict__ q, const bf16_t* __restrict__ k,
    const bf16_t* __restrict__ vT, const float* __restrict__ aqw,
    bf16_t* __restrict__ out) {
  constexpr int S = 2048, LDK = 72;
  __shared__ __align__(16) bf16_t Ks[64 * LDK];
  __shared__ __align__(16) bf16_t Vs[64 * LDK];
  __shared__ __align__(16) bf16_t Ps[4 * 16 * LDK];
  __shared__ bf16_t Ql[64 * LDK];
  __shared__ float segp[64][4];

  const int tid = threadIdx.x, w = tid >> 6, lane = tid & 63;
  const int quad = lane >> 4, tc = lane & 15;
  const int bh = blockIdx.y, q0 = blockIdx.x * 64;
  const bf16_t* qg = q + ((size_t)bh * S + q0) * 64;
  const bf16_t* kg = k + (size_t)bh * S * 64;
  const bf16_t* vg = vT + (size_t)bh * 64 * S;

  // quantum: cumprod(cos(q)) per row, 4 threads/row
  {
    const int rr = tid >> 2, ss = tid & 3;
    const bf16_t* qr = qg + rr * 64 + ss * 16;
    float c[16], p = 1.f;
#pragma unroll
    for (int j2 = 0; j2 < 16; ++j2) {
      c[j2] = __cosf((float)qr[j2]);
      p *= c[j2];
    }
    segp[rr][ss] = p;
    __syncthreads();
    float pre = 1.f;
    for (int u = 0; u < ss; ++u) pre *= segp[rr][u];
#pragma unroll
    for (int j2 = 0; j2 < 16; ++j2) {
      pre *= c[j2];
      Ql[rr * LDK + ss * 16 + j2] = (bf16_t)pre;
    }
  }

  // Q fragment (B-operand of S^T = K Q^T), pre-scaled by 1/8
  bf16x8 aq[2];
  {
    const int qrow = w * 16 + tc;
#pragma unroll
    for (int ks = 0; ks < 2; ++ks) {
      bf16x8 t = *(const bf16x8*)(qg + qrow * 64 + ks * 32 + quad * 8);
#pragma unroll
      for (int e = 0; e < 8; ++e) t[e] = (bf16_t)((float)t[e] * 0.125f);
      aq[ks] = t;
    }
  }

  float lacc = 0.f;
  f32x4 o[4] = {};
  bf16_t* Pw = &Ps[w * 16 * LDK];

  const int strow = tid >> 2, stcol = (tid & 3) * 16;

  for (int kt = 0; kt < S; kt += 64) {
    __syncthreads();  // WAR on Ks/Vs
    {
      bf16x8 k0v = *(const bf16x8*)(kg + (size_t)(kt + strow) * 64 + stcol);
      bf16x8 k1v = *(const bf16x8*)(kg + (size_t)(kt + strow) * 64 + stcol + 8);
      bf16x8 v0v = *(const bf16x8*)(vg + (size_t)strow * S + kt + stcol);
      bf16x8 v1v = *(const bf16x8*)(vg + (size_t)strow * S + kt + stcol + 8);
      *(bf16x8*)&Ks[strow * LDK + stcol] = k0v;
      *(bf16x8*)&Ks[strow * LDK + stcol + 8] = k1v;
      *(bf16x8*)&Vs[strow * LDK + stcol] = v0v;
      *(bf16x8*)&Vs[strow * LDK + stcol + 8] = v1v;
    }
    __syncthreads();

    // S^T tile: rows = keys, cols = 16 q-rows
    f32x4 sf[4] = {};
#pragma unroll
    for (int ks = 0; ks < 2; ++ks) {
#pragma unroll
      for (int nt = 0; nt < 4; ++nt) {
        bf16x8 ak = *(const bf16x8*)&Ks[(nt * 16 + tc) * LDK + ks * 32 + quad * 8];
        sf[nt] = __builtin_amdgcn_mfma_f32_16x16x32_bf16(ak, aq[ks], sf[nt], 0, 0, 0);
      }
    }

    // p = exp(s); keys contiguous per lane -> b64 writes
#pragma unroll
    for (int nt = 0; nt < 4; ++nt) {
      u16x4 pk;
      float ps = 0.f;
#pragma unroll
      for (int r = 0; r < 4; ++r) {
        const float p = __expf(sf[nt][r]);
        ps += p;
        pk[r] = bf16_bits(p);
      }
      lacc += ps;
      *(u16x4*)&Pw[tc * LDK + nt * 16 + quad * 4] = pk;
    }
    asm volatile("s_waitcnt lgkmcnt(0)" ::: "memory");

    // O += P V
#pragma unroll
    for (int ks = 0; ks < 2; ++ks) {
      bf16x8 ap = *(const bf16x8*)&Pw[tc * LDK + ks * 32 + quad * 8];
#pragma unroll
      for (int j = 0; j < 4; ++j) {
        bf16x8 bv = *(const bf16x8*)&Vs[(j * 16 + tc) * LDK + ks * 32 + quad * 8];
        o[j] = __builtin_amdgcn_mfma_f32_16x16x32_bf16(ap, bv, o[j], 0, 0, 0);
      }
    }
  }

  lacc += __shfl_xor(lacc, 16, 64);
  lacc += __shfl_xor(lacc, 32, 64);

  const float wsig = 1.f / (1.f + __expf(-aqw[0]));
  const int b = bh >> 4, h = bh & 15;
#pragma unroll
  for (int r = 0; r < 4; ++r) {
    const int lr = quad * 4 + r;
    const float linv = 1.f / __shfl(lacc, lr, 64);
    const int sg = q0 + w * 16 + lr;
#pragma unroll
    for (int j = 0; j < 4; ++j) {
      const int d = j * 16 + tc;
      const float cl = o[j][r] * linv;
      const float qv = (float)Ql[(w * 16 + lr) * LDK + d];
      out[((size_t)(b * 2048 + sg)) * 1024 + h * 64 + d] =
          (bf16_t)(wsig * qv + (1.f - wsig) * cl);
    }
  }
}

// ---------------------------------------------------------------------------
// LN1 + cumprod-scan fused: one block per row. Contiguous per-thread layout.
// x1 = LN(res); q2 = cumprod(cos(x1)) along the row.
// ---------------------------------------------------------------------------
__global__ __launch_bounds__(256) void ln1scan_kernel(
    const float* __restrict__ res, const float* __restrict__ g,
    const float* __restrict__ bta, bf16_t* __restrict__ x1,
    bf16_t* __restrict__ q2) {
  const int row = blockIdx.x;
  const int tid = threadIdx.x, w = tid >> 6, lane = tid & 63;
  f32x4 v = *(const f32x4*)&res[(size_t)row * 1024 + tid * 4];
  float s = v[0] + v[1] + v[2] + v[3];
  float sq = v[0] * v[0] + v[1] * v[1] + v[2] * v[2] + v[3] * v[3];
#pragma unroll
  for (int off = 32; off >= 1; off >>= 1) {
    s += __shfl_xor(s, off, 64);
    sq += __shfl_xor(sq, off, 64);
  }
  __shared__ float rs[4], rq[4], wtot[4];
  if (lane == 0) {
    rs[w] = s;
    rq[w] = sq;
  }
  __syncthreads();
  s = rs[0] + rs[1] + rs[2] + rs[3];
  sq = rq[0] + rq[1] + rq[2] + rq[3];
  const float mean = s * (1.f / 1024.f);
  const float var = fmaxf(sq * (1.f / 1024.f) - mean * mean, 0.f);
  const float rstd = rsqrtf(var + 1e-5f);

  const f32x4 gv = *(const f32x4*)&g[tid * 4];
  const f32x4 bv = *(const f32x4*)&bta[tid * 4];
  float c[4], p = 1.f;
  u16x4 xb;
#pragma unroll
  for (int i = 0; i < 4; ++i) {
    const float y = (v[i] - mean) * rstd * gv[i] + bv[i];
    const bf16_t yb = (bf16_t)y;
    xb[i] = __builtin_bit_cast(unsigned short, yb);
    c[i] = __cosf((float)yb);
    p *= c[i];
  }
  *(u16x4*)&x1[(size_t)row * 1024 + tid * 4] = xb;

  // block-wide inclusive scan of per-thread products
  float ip = p;
#pragma unroll
  for (int off = 1; off < 64; off <<= 1) {
    const float t = __shfl_up(ip, off, 64);
    if (lane >= off) ip *= t;
  }
  if (lane == 63) wtot[w] = ip;
  __syncthreads();
  float carry = 1.f;
  for (int u = 0; u < w; ++u) carry *= wtot[u];
  float run = __shfl_up(ip, 1, 64);
  if (lane == 0) run = 1.f;
  run *= carry;
  u16x4 qv;
#pragma unroll
  for (int i = 0; i < 4; ++i) {
    run *= c[i];
    qv[i] = bf16_bits(run);
  }
  *(u16x4*)&q2[(size_t)row * 1024 + tid * 4] = qv;
}

// ---------------------------------------------------------------------------
// LN2: f32 in, f32 out (contiguous layout)
// ---------------------------------------------------------------------------
__global__ __launch_bounds__(256) void ln2_kernel(
    const float* __restrict__ res, const float* __restrict__ g,
    const float* __restrict__ bta, float* __restrict__ out) {
  const int row = blockIdx.x;
  const int tid = threadIdx.x, w = tid >> 6, lane = tid & 63;
  f32x4 v = *(const f32x4*)&res[(size_t)row * 1024 + tid * 4];
  float s = v[0] + v[1] + v[2] + v[3];
  float sq = v[0] * v[0] + v[1] * v[1] + v[2] * v[2] + v[3] * v[3];
#pragma unroll
  for (int off = 32; off >= 1; off >>= 1) {
    s += __shfl_xor(s, off, 64);
    sq += __shfl_xor(sq, off, 64);
  }
  __shared__ float rs[4], rq[4];
  if (lane == 0) {
    rs[w] = s;
    rq[w] = sq;
  }
  __syncthreads();
  s = rs[0] + rs[1] + rs[2] + rs[3];
  sq = rq[0] + rq[1] + rq[2] + rq[3];
  const float mean = s * (1.f / 1024.f);
  const float var = fmaxf(sq * (1.f / 1024.f) - mean * mean, 0.f);
  const float rstd = rsqrtf(var + 1e-5f);
  const f32x4 gv = *(const f32x4*)&g[tid * 4];
  const f32x4 bv = *(const f32x4*)&bta[tid * 4];
  f32x4 y;
#pragma unroll
  for (int i = 0; i < 4; ++i) y[i] = (v[i] - mean) * rstd * gv[i] + bv[i];
  *(f32x4*)&out[(size_t)row * 1024 + tid * 4] = y;
}

// ---------------------------------------------------------------------------
extern "C" void kernel_launch(void* const* d_in, const int* in_sizes, int n_in,
                              void* d_out, int out_size, void* d_ws,
                              size_t ws_size, hipStream_t stream) {
  (void)in_sizes;
  (void)n_in;
  (void)out_size;
  (void)ws_size;
  const float* x = (const float*)d_in[0];
  const float* wq = (const float*)d_in[2];
  const float* wk = (const float*)d_in[3];
  const float* wv = (const float*)d_in[4];
  const float* wo = (const float*)d_in[5];
  const float* attn_qw = (const float*)d_in[7];
  const float* w1 = (const float*)d_in[8];
  const float* b1 = (const float*)d_in[9];
  const float* w2 = (const float*)d_in[10];
  const float* b2 = (const float*)d_in[11];
  const float* ffn_qw = (const float*)d_in[13];
  const float* ln1_g = (const float*)d_in[14];
  const float* ln1_b = (const float*)d_in[15];
  const float* ln2_g = (const float*)d_in[16];
  const float* ln2_b = (const float*)d_in[17];

  char* ws = (char*)d_ws;
  char* wsout = (char*)d_out;
  // ws (<=30 MB):
  bf16_t* wT3 = (bf16_t*)(ws + 0);            // [0,6M)  wo|w1|w2 T (persists)
  bf16_t* wqkvT = (bf16_t*)(ws + 6 * MB);     // [6,12M)  dies after VT GEMM
  bf16_t* xc = (bf16_t*)(ws + 12 * MB);       // [12,20M) dies after VT GEMM
  bf16_t* qb = (bf16_t*)(ws + 20 * MB);       // [20,28M) dies after attn
  bf16_t* aout = (bf16_t*)(ws + 6 * MB);      // [6,14M)  after attn
  float* res = (float*)(ws + 14 * MB);        // [14,30M) after WO
  bf16_t* x1 = (bf16_t*)(ws + 6 * MB);        // [6,14M)  after LN1 (aout dead)
  float* res2 = (float*)(ws + 14 * MB);       // [14,30M)
  // d_out (16 MB) as scratch:
  bf16_t* kb = (bf16_t*)(wsout + 0);          // [0,8M)   dies after attn
  bf16_t* vTb = (bf16_t*)(wsout + 8 * MB);    // [8,16M)  dies after attn
  bf16_t* q2 = (bf16_t*)(wsout + 0);          // [0,8M)   after attn
  bf16_t* hbuf = (bf16_t*)(wsout + 8 * MB);   // [8,16M)  after attn

  const dim3 tb(256);

  convx_kernel<<<2048, tb, 0, stream>>>(x, xc);
  tconv3_kernel<<<dim3(96, 32), tb, 0, stream>>>(wq, wk, wv, wqkvT);
  tconv3_kernel<<<dim3(96, 32), tb, 0, stream>>>(wo, w1, w2, wT3);

  // Q,K: [4096 x 2048] = xc @ [wqT|wkT]^T
  gemm_bt_kernel<EPI_QK, 4><<<dim3(16, 32), tb, 0, stream>>>(
      xc, wqkvT, qb, kb, nullptr, nullptr, nullptr, nullptr);
  // V^T: [1024 x 4096] = wvT @ xc^T
  gemm_bt_kernel<EPI_VT, 2><<<dim3(32, 16), tb, 0, stream>>>(
      wqkvT + 2 * 1024 * 1024, xc, vTb, nullptr, nullptr, nullptr, nullptr, nullptr);

  attn_kernel<<<dim3(32, 32), tb, 0, stream>>>(qb, kb, vTb, attn_qw, aout);

  gemm_bt_kernel<EPI_WO, 2><<<dim3(8, 64), tb, 0, stream>>>(
      aout, wT3, res, nullptr, x, nullptr, nullptr, nullptr);

  ln1scan_kernel<<<4096, tb, 0, stream>>>(res, ln1_g, ln1_b, x1, q2);

  gemm_bt_kernel<EPI_W1, 2><<<dim3(8, 64), tb, 0, stream>>>(
      x1, wT3 + 1024 * 1024, hbuf, nullptr, nullptr, q2, b1, ffn_qw);

  gemm_bt_kernel<EPI_W2, 2><<<dim3(8, 64), tb, 0, stream>>>(
      hbuf, wT3 + 2 * 1024 * 1024, res2, nullptr, nullptr, x1, b2, nullptr);

  ln2_kernel<<<4096, tb, 0, stream>>>(res2, ln2_g, ln2_b, (float*)d_out);
}

// Round 8
// 303.707 us; speedup vs baseline: 1.4977x; 1.0173x over previous
//
#include <hip/hip_runtime.h>
#include <hip/hip_bf16.h>
#include <cmath>
#include <cstdint>

// ---------------------------------------------------------------------------
// QuantumTransformerBlock. Inputs f32, output f32. Internals bf16 MFMA.
// R8: attention 2 q-subtiles/wave (LDS instrs/MFMA 1.5->0.9; it was 82%
//     LDS-pipe-bound), q-tile 128/block; QK+VT merged into one dispatch;
//     prep (convx + 2x tconv3) merged. 8 dispatches total.
// ---------------------------------------------------------------------------

typedef __bf16 bf16_t;
typedef __bf16 bf16x8 __attribute__((ext_vector_type(8)));
typedef float f32x4 __attribute__((ext_vector_type(4)));
typedef unsigned short u16x4 __attribute__((ext_vector_type(4)));

#define DEV_INLINE __device__ __forceinline__
#define MB 1048576

DEV_INLINE void gload16(const void* g, void* lds) {
  __builtin_amdgcn_global_load_lds(
      (const __attribute__((address_space(1))) unsigned int*)g,
      (__attribute__((address_space(3))) unsigned int*)lds, 16, 0, 0);
}

DEV_INLINE unsigned short bf16_bits(float f) {
  bf16_t b = (bf16_t)f;
  return __builtin_bit_cast(unsigned short, b);
}

// ---------------------------------------------------------------------------
// prep: [0,2048) convx  x f32 -> bf16
//       [2048,5120) tconv3 wq|wk|wv -> wqkvT[3072][1024]
//       [5120,8192) tconv3 wo|w1|w2 -> wT3[3072][1024]
// ---------------------------------------------------------------------------
__global__ __launch_bounds__(256) void prep_kernel(
    const float* __restrict__ x, const float* __restrict__ wq,
    const float* __restrict__ wk, const float* __restrict__ wv,
    const float* __restrict__ wo, const float* __restrict__ w1,
    const float* __restrict__ w2, bf16_t* __restrict__ xc,
    bf16_t* __restrict__ wqkvT, bf16_t* __restrict__ wT3) {
  __shared__ bf16_t t[32][33];
  const int bid = blockIdx.x;
  if (bid < 2048) {
    const size_t i0 = ((size_t)bid * 256 + threadIdx.x) * 8;
    bf16x8 v;
#pragma unroll
    for (int j = 0; j < 8; ++j) v[j] = (bf16_t)x[i0 + j];
    *(bf16x8*)(xc + i0) = v;
    return;
  }
  const int grp = (bid - 2048) / 3072;  // 0 -> wqkvT, 1 -> wT3
  const int tcb = (bid - 2048) - grp * 3072;
  const int mi = tcb >> 10;
  const float* src;
  bf16_t* dst;
  if (grp == 0) {
    src = (mi == 0) ? wq : (mi == 1) ? wk : wv;
    dst = wqkvT;
  } else {
    src = (mi == 0) ? wo : (mi == 1) ? w1 : w2;
    dst = wT3;
  }
  const int rem = tcb & 1023;
  const int bx = (rem & 31) * 32, by = (rem >> 5) * 32;
  const int tx = threadIdx.x & 31, ty = threadIdx.x >> 5;
#pragma unroll
  for (int i = 0; i < 4; ++i)
    t[ty + i * 8][tx] = (bf16_t)src[(size_t)(by + ty + i * 8) * 1024 + bx + tx];
  __syncthreads();
#pragma unroll
  for (int i = 0; i < 4; ++i)
    dst[(size_t)(mi * 1024 + bx + ty + i * 8) * 1024 + by + tx] = t[tx][ty + i * 8];
}

// ---------------------------------------------------------------------------
// merged QK + VT GEMM. blocks [0,512): QK  C[4096 x 2048] = xc @ wqkT|wkT^T
//                      blocks [512,768): VT C[1024 x 4096] = wvT @ xc^T
// BM=BN=128, BK=64, 4 waves 2x2, IM=4 (m97 structure).
// ---------------------------------------------------------------------------
__global__ __launch_bounds__(256) void qkvvt_kernel(
    const bf16_t* __restrict__ xc, const bf16_t* __restrict__ wqkvT,
    bf16_t* __restrict__ qb, bf16_t* __restrict__ kb,
    bf16_t* __restrict__ vTb) {
  constexpr int K = 1024, BK = 64;
  __shared__ __align__(16) bf16_t As[128 * BK];
  __shared__ __align__(16) bf16_t Bs[128 * BK];

  const int tid = threadIdx.x;
  const int w = tid >> 6, lane = tid & 63;
  const int quad = lane >> 4, tc = lane & 15;
  const int bid = blockIdx.x;
  const int isqk = (bid < 512);
  int m0, n0;
  const bf16_t *Ab, *Bb;
  if (isqk) {
    n0 = (bid & 15) * 128;
    m0 = (bid >> 4) * 128;
    Ab = xc + (size_t)m0 * K;
    Bb = wqkvT + (size_t)n0 * K;
  } else {
    const int t = bid - 512;
    n0 = (t & 31) * 128;
    m0 = (t >> 5) * 128;
    Ab = wqkvT + (size_t)(2 * 1024 * 1024) + (size_t)m0 * K;
    Bb = xc + (size_t)n0 * K;
  }
  const int wm = (w >> 1) * 64, wn = (w & 1) * 64;
  const int srow = lane >> 3, scol = (lane & 7) * 8;

  f32x4 acc[4][4] = {};

  for (int k0 = 0; k0 < K; k0 += BK) {
    __syncthreads();
#pragma unroll
    for (int it = 0; it < 4; ++it) {
      const int rbase = w * 32 + it * 8;
      gload16(Ab + (size_t)(rbase + srow) * K + k0 + scol, &As[rbase * BK]);
      gload16(Bb + (size_t)(rbase + srow) * K + k0 + scol, &Bs[rbase * BK]);
    }
    __syncthreads();
#pragma unroll
    for (int ks = 0; ks < 2; ++ks) {
      bf16x8 af[4], bfv[4];
#pragma unroll
      for (int i = 0; i < 4; ++i)
        af[i] = *(const bf16x8*)&As[(wm + i * 16 + tc) * BK + ks * 32 + quad * 8];
#pragma unroll
      for (int j = 0; j < 4; ++j)
        bfv[j] = *(const bf16x8*)&Bs[(wn + j * 16 + tc) * BK + ks * 32 + quad * 8];
#pragma unroll
      for (int i = 0; i < 4; ++i)
#pragma unroll
        for (int j = 0; j < 4; ++j)
          acc[i][j] = __builtin_amdgcn_mfma_f32_16x16x32_bf16(af[i], bfv[j],
                                                              acc[i][j], 0, 0, 0);
    }
  }

#pragma unroll
  for (int i = 0; i < 4; ++i) {
#pragma unroll
    for (int j = 0; j < 4; ++j) {
      const int row0 = m0 + wm + i * 16 + quad * 4;
      const int col = n0 + wn + j * 16 + tc;
      if (isqk) {
        const int part = col >> 10, e = col & 1023, hh = e >> 6, d = e & 63;
        bf16_t* dst = part ? kb : qb;
#pragma unroll
        for (int r = 0; r < 4; ++r) {
          const int row = row0 + r;
          const int b = row >> 11, s = row & 2047;
          dst[((size_t)(b * 16 + hh) * 2048 + s) * 64 + d] = (bf16_t)acc[i][j][r];
        }
      } else {
        const int b = col >> 11, s = col & 2047;
#pragma unroll
        for (int r = 0; r < 4; ++r) {
          vTb[((size_t)(b * 1024 + row0 + r)) * 2048 + s] = (bf16_t)acc[i][j][r];
        }
      }
    }
  }
}

// ---------------------------------------------------------------------------
// W-GEMM C[M,N] = A[M,K] * Bt[N,K]^T. BM=64 (IM=2), BN=128, BK=64.
// ---------------------------------------------------------------------------
enum { EPI_WO = 2, EPI_W1 = 3, EPI_W2 = 4 };

template <int EPI>
__global__ __launch_bounds__(256) void gemm_bt_kernel(
    const bf16_t* __restrict__ A, const bf16_t* __restrict__ Bt,
    void* __restrict__ o0, const float* __restrict__ auxf,
    const bf16_t* __restrict__ auxb, const float* __restrict__ bias,
    const float* __restrict__ scal) {
  constexpr int K = 1024, IM = 2, BM = 64, BK = 64;
  __shared__ __align__(16) bf16_t As[BM * BK];
  __shared__ __align__(16) bf16_t Bs[128 * BK];

  const int tid = threadIdx.x;
  const int w = tid >> 6, lane = tid & 63;
  const int quad = lane >> 4, tc = lane & 15;
  const int m0 = blockIdx.y * BM, n0 = blockIdx.x * 128;
  const int wm = (w >> 1) * 32, wn = (w & 1) * 64;
  const int srow = lane >> 3, scol = (lane & 7) * 8;

  f32x4 acc[IM][4] = {};

  const bf16_t* Ab = A + (size_t)m0 * K;
  const bf16_t* Bb = Bt + (size_t)n0 * K;

  for (int k0 = 0; k0 < K; k0 += BK) {
    __syncthreads();
#pragma unroll
    for (int it = 0; it < IM; ++it) {
      const int rbase = w * (IM * 8) + it * 8;
      gload16(Ab + (size_t)(rbase + srow) * K + k0 + scol, &As[rbase * BK]);
    }
#pragma unroll
    for (int it = 0; it < 4; ++it) {
      const int rbase = w * 32 + it * 8;
      gload16(Bb + (size_t)(rbase + srow) * K + k0 + scol, &Bs[rbase * BK]);
    }
    __syncthreads();
#pragma unroll
    for (int ks = 0; ks < 2; ++ks) {
      bf16x8 af[IM], bfv[4];
#pragma unroll
      for (int i = 0; i < IM; ++i)
        af[i] = *(const bf16x8*)&As[(wm + i * 16 + tc) * BK + ks * 32 + quad * 8];
#pragma unroll
      for (int j = 0; j < 4; ++j)
        bfv[j] = *(const bf16x8*)&Bs[(wn + j * 16 + tc) * BK + ks * 32 + quad * 8];
#pragma unroll
      for (int i = 0; i < IM; ++i)
#pragma unroll
        for (int j = 0; j < 4; ++j)
          acc[i][j] = __builtin_amdgcn_mfma_f32_16x16x32_bf16(af[i], bfv[j],
                                                              acc[i][j], 0, 0, 0);
    }
  }

  float wsig = 0.f;
  if (EPI == EPI_W1) wsig = 1.f / (1.f + __expf(-scal[0]));

#pragma unroll
  for (int i = 0; i < IM; ++i) {
#pragma unroll
    for (int j = 0; j < 4; ++j) {
      const int row0 = m0 + wm + i * 16 + quad * 4;
      const int col = n0 + wn + j * 16 + tc;
      if (EPI == EPI_WO) {
#pragma unroll
        for (int r = 0; r < 4; ++r) {
          const int row = row0 + r;
          ((float*)o0)[(size_t)row * 1024 + col] =
              acc[i][j][r] + auxf[(size_t)row * 1024 + col];
        }
      } else if (EPI == EPI_W1) {
#pragma unroll
        for (int r = 0; r < 4; ++r) {
          const int row = row0 + r;
          float c = fmaxf(acc[i][j][r] + bias[col], 0.f);
          const float qv = (float)auxb[(size_t)row * 1024 + col];
          ((bf16_t*)o0)[(size_t)row * 1024 + col] =
              (bf16_t)(wsig * qv + (1.f - wsig) * c);
        }
      } else {  // EPI_W2
#pragma unroll
        for (int r = 0; r < 4; ++r) {
          const int row = row0 + r;
          ((float*)o0)[(size_t)row * 1024 + col] =
              acc[i][j][r] + bias[col] + (float)auxb[(size_t)row * 1024 + col];
        }
      }
    }
  }
}

// ---------------------------------------------------------------------------
// Flash attention: q-tile 128/block, each wave 32 q-rows (2 subtiles).
// LDS strides 72; no-max softmax; S^T = K*Q^T; wave-local Ps.
// ---------------------------------------------------------------------------
__global__ __launch_bounds__(256) void attn_kernel(
    const bf16_t* __restrict__ q, const bf16_t* __restrict__ k,
    const bf16_t* __restrict__ vT, const float* __restrict__ aqw,
    bf16_t* __restrict__ out) {
  constexpr int S = 2048, LDK = 72;
  __shared__ __align__(16) bf16_t Ks[64 * LDK];
  __shared__ __align__(16) bf16_t Vs[64 * LDK];
  __shared__ __align__(16) bf16_t Ps[4][32 * LDK];
  __shared__ bf16_t Ql[128 * LDK];
  __shared__ float segp[128][4];

  const int tid = threadIdx.x, w = tid >> 6, lane = tid & 63;
  const int quad = lane >> 4, tc = lane & 15;
  const int bh = blockIdx.y, q0 = blockIdx.x * 128;
  const bf16_t* qg = q + ((size_t)bh * S + q0) * 64;
  const bf16_t* kg = k + (size_t)bh * S * 64;
  const bf16_t* vg = vT + (size_t)bh * 64 * S;

  // quantum: cumprod(cos(q)) for 128 rows; 4 threads/row, 2 passes
  {
    float c[2][16];
    const int ss = tid & 3;
#pragma unroll
    for (int pass = 0; pass < 2; ++pass) {
      const int rr = pass * 64 + (tid >> 2);
      const bf16_t* qr = qg + rr * 64 + ss * 16;
      float p = 1.f;
#pragma unroll
      for (int j2 = 0; j2 < 16; ++j2) {
        c[pass][j2] = __cosf((float)qr[j2]);
        p *= c[pass][j2];
      }
      segp[rr][ss] = p;
    }
    __syncthreads();
#pragma unroll
    for (int pass = 0; pass < 2; ++pass) {
      const int rr = pass * 64 + (tid >> 2);
      float pre = 1.f;
      for (int u = 0; u < ss; ++u) pre *= segp[rr][u];
#pragma unroll
      for (int j2 = 0; j2 < 16; ++j2) {
        pre *= c[pass][j2];
        Ql[rr * LDK + ss * 16 + j2] = (bf16_t)pre;
      }
    }
  }

  // Q fragments (B-operand of S^T = K Q^T), pre-scaled by 1/8
  bf16x8 aq[2][2];
#pragma unroll
  for (int qs = 0; qs < 2; ++qs) {
    const int qrow = w * 32 + qs * 16 + tc;
#pragma unroll
    for (int ks = 0; ks < 2; ++ks) {
      bf16x8 t = *(const bf16x8*)(qg + qrow * 64 + ks * 32 + quad * 8);
#pragma unroll
      for (int e = 0; e < 8; ++e) t[e] = (bf16_t)((float)t[e] * 0.125f);
      aq[qs][ks] = t;
    }
  }

  float lacc[2] = {0.f, 0.f};
  f32x4 o[2][4] = {};
  bf16_t* Pw = Ps[w];

  const int strow = tid >> 2, stcol = (tid & 3) * 16;

  for (int kt = 0; kt < S; kt += 64) {
    __syncthreads();  // WAR on Ks/Vs
    {
      bf16x8 k0v = *(const bf16x8*)(kg + (size_t)(kt + strow) * 64 + stcol);
      bf16x8 k1v = *(const bf16x8*)(kg + (size_t)(kt + strow) * 64 + stcol + 8);
      bf16x8 v0v = *(const bf16x8*)(vg + (size_t)strow * S + kt + stcol);
      bf16x8 v1v = *(const bf16x8*)(vg + (size_t)strow * S + kt + stcol + 8);
      *(bf16x8*)&Ks[strow * LDK + stcol] = k0v;
      *(bf16x8*)&Ks[strow * LDK + stcol + 8] = k1v;
      *(bf16x8*)&Vs[strow * LDK + stcol] = v0v;
      *(bf16x8*)&Vs[strow * LDK + stcol + 8] = v1v;
    }
    __syncthreads();

    // S^T tiles for both q-subtiles; Ks reads shared
    f32x4 sf[2][4] = {};
#pragma unroll
    for (int ks = 0; ks < 2; ++ks) {
#pragma unroll
      for (int nt = 0; nt < 4; ++nt) {
        bf16x8 ak = *(const bf16x8*)&Ks[(nt * 16 + tc) * LDK + ks * 32 + quad * 8];
        sf[0][nt] = __builtin_amdgcn_mfma_f32_16x16x32_bf16(ak, aq[0][ks], sf[0][nt], 0, 0, 0);
        sf[1][nt] = __builtin_amdgcn_mfma_f32_16x16x32_bf16(ak, aq[1][ks], sf[1][nt], 0, 0, 0);
      }
    }

    // p = exp(s); keys contiguous per lane -> b64 writes
#pragma unroll
    for (int qs = 0; qs < 2; ++qs) {
#pragma unroll
      for (int nt = 0; nt < 4; ++nt) {
        u16x4 pk;
        float ps = 0.f;
#pragma unroll
        for (int r = 0; r < 4; ++r) {
          const float p = __expf(sf[qs][nt][r]);
          ps += p;
          pk[r] = bf16_bits(p);
        }
        lacc[qs] += ps;
        *(u16x4*)&Pw[(qs * 16 + tc) * LDK + nt * 16 + quad * 4] = pk;
      }
    }
    asm volatile("s_waitcnt lgkmcnt(0)" ::: "memory");

    // O += P V ; Vs reads shared across subtiles
#pragma unroll
    for (int ks = 0; ks < 2; ++ks) {
      bf16x8 ap0 = *(const bf16x8*)&Pw[tc * LDK + ks * 32 + quad * 8];
      bf16x8 ap1 = *(const bf16x8*)&Pw[(16 + tc) * LDK + ks * 32 + quad * 8];
#pragma unroll
      for (int j = 0; j < 4; ++j) {
        bf16x8 bv = *(const bf16x8*)&Vs[(j * 16 + tc) * LDK + ks * 32 + quad * 8];
        o[0][j] = __builtin_amdgcn_mfma_f32_16x16x32_bf16(ap0, bv, o[0][j], 0, 0, 0);
        o[1][j] = __builtin_amdgcn_mfma_f32_16x16x32_bf16(ap1, bv, o[1][j], 0, 0, 0);
      }
    }
  }

#pragma unroll
  for (int qs = 0; qs < 2; ++qs) {
    lacc[qs] += __shfl_xor(lacc[qs], 16, 64);
    lacc[qs] += __shfl_xor(lacc[qs], 32, 64);
  }

  const float wsig = 1.f / (1.f + __expf(-aqw[0]));
  const int b = bh >> 4, h = bh & 15;
#pragma unroll
  for (int qs = 0; qs < 2; ++qs) {
#pragma unroll
    for (int r = 0; r < 4; ++r) {
      const int lr = quad * 4 + r;
      const float linv = 1.f / __shfl(lacc[qs], lr, 64);
      const int lrow = w * 32 + qs * 16 + lr;
      const int sg = q0 + lrow;
#pragma unroll
      for (int j = 0; j < 4; ++j) {
        const int d = j * 16 + tc;
        const float cl = o[qs][j][r] * linv;
        const float qv = (float)Ql[lrow * LDK + d];
        out[((size_t)(b * 2048 + sg)) * 1024 + h * 64 + d] =
            (bf16_t)(wsig * qv + (1.f - wsig) * cl);
      }
    }
  }
}

// ---------------------------------------------------------------------------
// LN1 + cumprod-scan fused: one block per row.
// ---------------------------------------------------------------------------
__global__ __launch_bounds__(256) void ln1scan_kernel(
    const float* __restrict__ res, const float* __restrict__ g,
    const float* __restrict__ bta, bf16_t* __restrict__ x1,
    bf16_t* __restrict__ q2) {
  const int row = blockIdx.x;
  const int tid = threadIdx.x, w = tid >> 6, lane = tid & 63;
  f32x4 v = *(const f32x4*)&res[(size_t)row * 1024 + tid * 4];
  float s = v[0] + v[1] + v[2] + v[3];
  float sq = v[0] * v[0] + v[1] * v[1] + v[2] * v[2] + v[3] * v[3];
#pragma unroll
  for (int off = 32; off >= 1; off >>= 1) {
    s += __shfl_xor(s, off, 64);
    sq += __shfl_xor(sq, off, 64);
  }
  __shared__ float rs[4], rq[4], wtot[4];
  if (lane == 0) {
    rs[w] = s;
    rq[w] = sq;
  }
  __syncthreads();
  s = rs[0] + rs[1] + rs[2] + rs[3];
  sq = rq[0] + rq[1] + rq[2] + rq[3];
  const float mean = s * (1.f / 1024.f);
  const float var = fmaxf(sq * (1.f / 1024.f) - mean * mean, 0.f);
  const float rstd = rsqrtf(var + 1e-5f);

  const f32x4 gv = *(const f32x4*)&g[tid * 4];
  const f32x4 bv = *(const f32x4*)&bta[tid * 4];
  float c[4], p = 1.f;
  u16x4 xb;
#pragma unroll
  for (int i = 0; i < 4; ++i) {
    const float y = (v[i] - mean) * rstd * gv[i] + bv[i];
    const bf16_t yb = (bf16_t)y;
    xb[i] = __builtin_bit_cast(unsigned short, yb);
    c[i] = __cosf((float)yb);
    p *= c[i];
  }
  *(u16x4*)&x1[(size_t)row * 1024 + tid * 4] = xb;

  float ip = p;
#pragma unroll
  for (int off = 1; off < 64; off <<= 1) {
    const float t = __shfl_up(ip, off, 64);
    if (lane >= off) ip *= t;
  }
  if (lane == 63) wtot[w] = ip;
  __syncthreads();
  float carry = 1.f;
  for (int u = 0; u < w; ++u) carry *= wtot[u];
  float run = __shfl_up(ip, 1, 64);
  if (lane == 0) run = 1.f;
  run *= carry;
  u16x4 qv;
#pragma unroll
  for (int i = 0; i < 4; ++i) {
    run *= c[i];
    qv[i] = bf16_bits(run);
  }
  *(u16x4*)&q2[(size_t)row * 1024 + tid * 4] = qv;
}

// ---------------------------------------------------------------------------
// LN2: f32 in, f32 out
// ---------------------------------------------------------------------------
__global__ __launch_bounds__(256) void ln2_kernel(
    const float* __restrict__ res, const float* __restrict__ g,
    const float* __restrict__ bta, float* __restrict__ out) {
  const int row = blockIdx.x;
  const int tid = threadIdx.x, w = tid >> 6, lane = tid & 63;
  f32x4 v = *(const f32x4*)&res[(size_t)row * 1024 + tid * 4];
  float s = v[0] + v[1] + v[2] + v[3];
  float sq = v[0] * v[0] + v[1] * v[1] + v[2] * v[2] + v[3] * v[3];
#pragma unroll
  for (int off = 32; off >= 1; off >>= 1) {
    s += __shfl_xor(s, off, 64);
    sq += __shfl_xor(sq, off, 64);
  }
  __shared__ float rs[4], rq[4];
  if (lane == 0) {
    rs[w] = s;
    rq[w] = sq;
  }
  __syncthreads();
  s = rs[0] + rs[1] + rs[2] + rs[3];
  sq = rq[0] + rq[1] + rq[2] + rq[3];
  const float mean = s * (1.f / 1024.f);
  const float var = fmaxf(sq * (1.f / 1024.f) - mean * mean, 0.f);
  const float rstd = rsqrtf(var + 1e-5f);
  const f32x4 gv = *(const f32x4*)&g[tid * 4];
  const f32x4 bv = *(const f32x4*)&bta[tid * 4];
  f32x4 y;
#pragma unroll
  for (int i = 0; i < 4; ++i) y[i] = (v[i] - mean) * rstd * gv[i] + bv[i];
  *(f32x4*)&out[(size_t)row * 1024 + tid * 4] = y;
}

// ---------------------------------------------------------------------------
extern "C" void kernel_launch(void* const* d_in, const int* in_sizes, int n_in,
                              void* d_out, int out_size, void* d_ws,
                              size_t ws_size, hipStream_t stream) {
  (void)in_sizes;
  (void)n_in;
  (void)out_size;
  (void)ws_size;
  const float* x = (const float*)d_in[0];
  const float* wq = (const float*)d_in[2];
  const float* wk = (const float*)d_in[3];
  const float* wv = (const float*)d_in[4];
  const float* wo = (const float*)d_in[5];
  const float* attn_qw = (const float*)d_in[7];
  const float* w1 = (const float*)d_in[8];
  const float* b1 = (const float*)d_in[9];
  const float* w2 = (const float*)d_in[10];
  const float* b2 = (const float*)d_in[11];
  const float* ffn_qw = (const float*)d_in[13];
  const float* ln1_g = (const float*)d_in[14];
  const float* ln1_b = (const float*)d_in[15];
  const float* ln2_g = (const float*)d_in[16];
  const float* ln2_b = (const float*)d_in[17];

  char* ws = (char*)d_ws;
  char* wsout = (char*)d_out;
  // ws (<=30 MB):
  bf16_t* wT3 = (bf16_t*)(ws + 0);            // [0,6M)  wo|w1|w2 T (persists)
  bf16_t* wqkvT = (bf16_t*)(ws + 6 * MB);     // [6,12M)  dies after QKVVT
  bf16_t* xc = (bf16_t*)(ws + 12 * MB);       // [12,20M) dies after QKVVT
  bf16_t* qb = (bf16_t*)(ws + 20 * MB);       // [20,28M) dies after attn
  bf16_t* aout = (bf16_t*)(ws + 6 * MB);      // [6,14M)  after attn
  float* res = (float*)(ws + 14 * MB);        // [14,30M) after WO
  bf16_t* x1 = (bf16_t*)(ws + 6 * MB);        // [6,14M)  after LN1 (aout dead)
  float* res2 = (float*)(ws + 14 * MB);       // [14,30M)
  // d_out (16 MB) as scratch:
  bf16_t* kb = (bf16_t*)(wsout + 0);          // [0,8M)   dies after attn
  bf16_t* vTb = (bf16_t*)(wsout + 8 * MB);    // [8,16M)  dies after attn
  bf16_t* q2 = (bf16_t*)(wsout + 0);          // [0,8M)   after attn
  bf16_t* hbuf = (bf16_t*)(wsout + 8 * MB);   // [8,16M)  after attn

  const dim3 tb(256);

  prep_kernel<<<8192, tb, 0, stream>>>(x, wq, wk, wv, wo, w1, w2, xc, wqkvT, wT3);

  qkvvt_kernel<<<768, tb, 0, stream>>>(xc, wqkvT, qb, kb, vTb);

  attn_kernel<<<dim3(16, 32), tb, 0, stream>>>(qb, kb, vTb, attn_qw, aout);

  gemm_bt_kernel<EPI_WO><<<dim3(8, 64), tb, 0, stream>>>(
      aout, wT3, res, x, nullptr, nullptr, nullptr);

  ln1scan_kernel<<<4096, tb, 0, stream>>>(res, ln1_g, ln1_b, x1, q2);

  gemm_bt_kernel<EPI_W1><<<dim3(8, 64), tb, 0, stream>>>(
      x1, wT3 + 1024 * 1024, hbuf, nullptr, q2, b1, ffn_qw);

  gemm_bt_kernel<EPI_W2><<<dim3(8, 64), tb, 0, stream>>>(
      hbuf, wT3 + 2 * 1024 * 1024, res2, nullptr, x1, b2, nullptr);

  ln2_kernel<<<4096, tb, 0, stream>>>(res2, ln2_g, ln2_b, (float*)d_out);
}

// Round 9
// 286.681 us; speedup vs baseline: 1.5867x; 1.0594x over previous
//
#include <hip/hip_runtime.h>
#include <hip/hip_bf16.h>
#include <cmath>
#include <cstdint>

// ---------------------------------------------------------------------------
// QuantumTransformerBlock. Inputs f32, output f32. Internals bf16 MFMA.
// R9: attention register-prefetch pipeline (hide K/V global latency inside
//     the barrier pair), exp2 trick (Q pre-scaled by 0.125*log2e), W-GEMMs
//     64x64 tiles (grid 1024 = 4 blocks/CU for latency overlap).
// ---------------------------------------------------------------------------

typedef __bf16 bf16_t;
typedef __bf16 bf16x8 __attribute__((ext_vector_type(8)));
typedef float f32x4 __attribute__((ext_vector_type(4)));
typedef unsigned short u16x4 __attribute__((ext_vector_type(4)));

#define DEV_INLINE __device__ __forceinline__
#define MB 1048576

DEV_INLINE void gload16(const void* g, void* lds) {
  __builtin_amdgcn_global_load_lds(
      (const __attribute__((address_space(1))) unsigned int*)g,
      (__attribute__((address_space(3))) unsigned int*)lds, 16, 0, 0);
}

DEV_INLINE unsigned short bf16_bits(float f) {
  bf16_t b = (bf16_t)f;
  return __builtin_bit_cast(unsigned short, b);
}

// ---------------------------------------------------------------------------
// prep: [0,2048) convx  x f32 -> bf16
//       [2048,5120) tconv3 wq|wk|wv -> wqkvT[3072][1024]
//       [5120,8192) tconv3 wo|w1|w2 -> wT3[3072][1024]
// ---------------------------------------------------------------------------
__global__ __launch_bounds__(256) void prep_kernel(
    const float* __restrict__ x, const float* __restrict__ wq,
    const float* __restrict__ wk, const float* __restrict__ wv,
    const float* __restrict__ wo, const float* __restrict__ w1,
    const float* __restrict__ w2, bf16_t* __restrict__ xc,
    bf16_t* __restrict__ wqkvT, bf16_t* __restrict__ wT3) {
  __shared__ bf16_t t[32][33];
  const int bid = blockIdx.x;
  if (bid < 2048) {
    const size_t i0 = ((size_t)bid * 256 + threadIdx.x) * 8;
    bf16x8 v;
#pragma unroll
    for (int j = 0; j < 8; ++j) v[j] = (bf16_t)x[i0 + j];
    *(bf16x8*)(xc + i0) = v;
    return;
  }
  const int grp = (bid - 2048) / 3072;  // 0 -> wqkvT, 1 -> wT3
  const int tcb = (bid - 2048) - grp * 3072;
  const int mi = tcb >> 10;
  const float* src;
  bf16_t* dst;
  if (grp == 0) {
    src = (mi == 0) ? wq : (mi == 1) ? wk : wv;
    dst = wqkvT;
  } else {
    src = (mi == 0) ? wo : (mi == 1) ? w1 : w2;
    dst = wT3;
  }
  const int rem = tcb & 1023;
  const int bx = (rem & 31) * 32, by = (rem >> 5) * 32;
  const int tx = threadIdx.x & 31, ty = threadIdx.x >> 5;
#pragma unroll
  for (int i = 0; i < 4; ++i)
    t[ty + i * 8][tx] = (bf16_t)src[(size_t)(by + ty + i * 8) * 1024 + bx + tx];
  __syncthreads();
#pragma unroll
  for (int i = 0; i < 4; ++i)
    dst[(size_t)(mi * 1024 + bx + ty + i * 8) * 1024 + by + tx] = t[tx][ty + i * 8];
}

// ---------------------------------------------------------------------------
// merged QK + VT GEMM. blocks [0,512): QK  C[4096 x 2048] = xc @ wqkT|wkT^T
//                      blocks [512,768): VT C[1024 x 4096] = wvT @ xc^T
// BM=BN=128, BK=64, 4 waves 2x2 (m97 structure).
// ---------------------------------------------------------------------------
__global__ __launch_bounds__(256) void qkvvt_kernel(
    const bf16_t* __restrict__ xc, const bf16_t* __restrict__ wqkvT,
    bf16_t* __restrict__ qb, bf16_t* __restrict__ kb,
    bf16_t* __restrict__ vTb) {
  constexpr int K = 1024, BK = 64;
  __shared__ __align__(16) bf16_t As[128 * BK];
  __shared__ __align__(16) bf16_t Bs[128 * BK];

  const int tid = threadIdx.x;
  const int w = tid >> 6, lane = tid & 63;
  const int quad = lane >> 4, tc = lane & 15;
  const int bid = blockIdx.x;
  const int isqk = (bid < 512);
  int m0, n0;
  const bf16_t *Ab, *Bb;
  if (isqk) {
    n0 = (bid & 15) * 128;
    m0 = (bid >> 4) * 128;
    Ab = xc + (size_t)m0 * K;
    Bb = wqkvT + (size_t)n0 * K;
  } else {
    const int t = bid - 512;
    n0 = (t & 31) * 128;
    m0 = (t >> 5) * 128;
    Ab = wqkvT + (size_t)(2 * 1024 * 1024) + (size_t)m0 * K;
    Bb = xc + (size_t)n0 * K;
  }
  const int wm = (w >> 1) * 64, wn = (w & 1) * 64;
  const int srow = lane >> 3, scol = (lane & 7) * 8;

  f32x4 acc[4][4] = {};

  for (int k0 = 0; k0 < K; k0 += BK) {
    __syncthreads();
#pragma unroll
    for (int it = 0; it < 4; ++it) {
      const int rbase = w * 32 + it * 8;
      gload16(Ab + (size_t)(rbase + srow) * K + k0 + scol, &As[rbase * BK]);
      gload16(Bb + (size_t)(rbase + srow) * K + k0 + scol, &Bs[rbase * BK]);
    }
    __syncthreads();
#pragma unroll
    for (int ks = 0; ks < 2; ++ks) {
      bf16x8 af[4], bfv[4];
#pragma unroll
      for (int i = 0; i < 4; ++i)
        af[i] = *(const bf16x8*)&As[(wm + i * 16 + tc) * BK + ks * 32 + quad * 8];
#pragma unroll
      for (int j = 0; j < 4; ++j)
        bfv[j] = *(const bf16x8*)&Bs[(wn + j * 16 + tc) * BK + ks * 32 + quad * 8];
#pragma unroll
      for (int i = 0; i < 4; ++i)
#pragma unroll
        for (int j = 0; j < 4; ++j)
          acc[i][j] = __builtin_amdgcn_mfma_f32_16x16x32_bf16(af[i], bfv[j],
                                                              acc[i][j], 0, 0, 0);
    }
  }

#pragma unroll
  for (int i = 0; i < 4; ++i) {
#pragma unroll
    for (int j = 0; j < 4; ++j) {
      const int row0 = m0 + wm + i * 16 + quad * 4;
      const int col = n0 + wn + j * 16 + tc;
      if (isqk) {
        const int part = col >> 10, e = col & 1023, hh = e >> 6, d = e & 63;
        bf16_t* dst = part ? kb : qb;
#pragma unroll
        for (int r = 0; r < 4; ++r) {
          const int row = row0 + r;
          const int b = row >> 11, s = row & 2047;
          dst[((size_t)(b * 16 + hh) * 2048 + s) * 64 + d] = (bf16_t)acc[i][j][r];
        }
      } else {
        const int b = col >> 11, s = col & 2047;
#pragma unroll
        for (int r = 0; r < 4; ++r) {
          vTb[((size_t)(b * 1024 + row0 + r)) * 2048 + s] = (bf16_t)acc[i][j][r];
        }
      }
    }
  }
}

// ---------------------------------------------------------------------------
// W-GEMM C[M,N] = A[M,K] * Bt[N,K]^T. BM=BN=64, BK=64, wave tile 32x32.
// Grid (16, 64) = 1024 blocks -> 4 blocks/CU.
// ---------------------------------------------------------------------------
enum { EPI_WO = 2, EPI_W1 = 3, EPI_W2 = 4 };

template <int EPI>
__global__ __launch_bounds__(256) void gemm_bt_kernel(
    const bf16_t* __restrict__ A, const bf16_t* __restrict__ Bt,
    void* __restrict__ o0, const float* __restrict__ auxf,
    const bf16_t* __restrict__ auxb, const float* __restrict__ bias,
    const float* __restrict__ scal) {
  constexpr int K = 1024, BK = 64;
  __shared__ __align__(16) bf16_t As[64 * BK];
  __shared__ __align__(16) bf16_t Bs[64 * BK];

  const int tid = threadIdx.x;
  const int w = tid >> 6, lane = tid & 63;
  const int quad = lane >> 4, tc = lane & 15;
  const int m0 = blockIdx.y * 64, n0 = blockIdx.x * 64;
  const int wm = (w >> 1) * 32, wn = (w & 1) * 32;
  const int srow = lane >> 3, scol = (lane & 7) * 8;

  f32x4 acc[2][2] = {};

  const bf16_t* Ab = A + (size_t)m0 * K;
  const bf16_t* Bb = Bt + (size_t)n0 * K;

  for (int k0 = 0; k0 < K; k0 += BK) {
    __syncthreads();
#pragma unroll
    for (int it = 0; it < 2; ++it) {
      const int rbase = w * 16 + it * 8;
      gload16(Ab + (size_t)(rbase + srow) * K + k0 + scol, &As[rbase * BK]);
      gload16(Bb + (size_t)(rbase + srow) * K + k0 + scol, &Bs[rbase * BK]);
    }
    __syncthreads();
#pragma unroll
    for (int ks = 0; ks < 2; ++ks) {
      bf16x8 af[2], bfv[2];
#pragma unroll
      for (int i = 0; i < 2; ++i)
        af[i] = *(const bf16x8*)&As[(wm + i * 16 + tc) * BK + ks * 32 + quad * 8];
#pragma unroll
      for (int j = 0; j < 2; ++j)
        bfv[j] = *(const bf16x8*)&Bs[(wn + j * 16 + tc) * BK + ks * 32 + quad * 8];
#pragma unroll
      for (int i = 0; i < 2; ++i)
#pragma unroll
        for (int j = 0; j < 2; ++j)
          acc[i][j] = __builtin_amdgcn_mfma_f32_16x16x32_bf16(af[i], bfv[j],
                                                              acc[i][j], 0, 0, 0);
    }
  }

  float wsig = 0.f;
  if (EPI == EPI_W1) wsig = 1.f / (1.f + __expf(-scal[0]));

#pragma unroll
  for (int i = 0; i < 2; ++i) {
#pragma unroll
    for (int j = 0; j < 2; ++j) {
      const int row0 = m0 + wm + i * 16 + quad * 4;
      const int col = n0 + wn + j * 16 + tc;
      if (EPI == EPI_WO) {
#pragma unroll
        for (int r = 0; r < 4; ++r) {
          const int row = row0 + r;
          ((float*)o0)[(size_t)row * 1024 + col] =
              acc[i][j][r] + auxf[(size_t)row * 1024 + col];
        }
      } else if (EPI == EPI_W1) {
#pragma unroll
        for (int r = 0; r < 4; ++r) {
          const int row = row0 + r;
          float c = fmaxf(acc[i][j][r] + bias[col], 0.f);
          const float qv = (float)auxb[(size_t)row * 1024 + col];
          ((bf16_t*)o0)[(size_t)row * 1024 + col] =
              (bf16_t)(wsig * qv + (1.f - wsig) * c);
        }
      } else {  // EPI_W2
#pragma unroll
        for (int r = 0; r < 4; ++r) {
          const int row = row0 + r;
          ((float*)o0)[(size_t)row * 1024 + col] =
              acc[i][j][r] + bias[col] + (float)auxb[(size_t)row * 1024 + col];
        }
      }
    }
  }
}

// ---------------------------------------------------------------------------
// Flash attention: q-tile 128/block, each wave 32 q-rows (2 subtiles).
// Register-prefetch pipeline for K/V staging; exp2 softmax (no-max);
// S^T = K*Q^T; wave-local Ps. LDS strides 72.
// ---------------------------------------------------------------------------
__global__ __launch_bounds__(256) void attn_kernel(
    const bf16_t* __restrict__ q, const bf16_t* __restrict__ k,
    const bf16_t* __restrict__ vT, const float* __restrict__ aqw,
    bf16_t* __restrict__ out) {
  constexpr int S = 2048, LDK = 72;
  __shared__ __align__(16) bf16_t Ks[64 * LDK];
  __shared__ __align__(16) bf16_t Vs[64 * LDK];
  __shared__ __align__(16) bf16_t Ps[4][32 * LDK];
  __shared__ bf16_t Ql[128 * LDK];
  __shared__ float segp[128][4];

  const int tid = threadIdx.x, w = tid >> 6, lane = tid & 63;
  const int quad = lane >> 4, tc = lane & 15;
  const int bh = blockIdx.y, q0 = blockIdx.x * 128;
  const bf16_t* qg = q + ((size_t)bh * S + q0) * 64;
  const bf16_t* kg = k + (size_t)bh * S * 64;
  const bf16_t* vg = vT + (size_t)bh * 64 * S;

  const int strow = tid >> 2, stcol = (tid & 3) * 16;

  // prefetch K/V tile 0 (latency overlaps the quantum section below)
  bf16x8 pk0 = *(const bf16x8*)(kg + (size_t)strow * 64 + stcol);
  bf16x8 pk1 = *(const bf16x8*)(kg + (size_t)strow * 64 + stcol + 8);
  bf16x8 pv0 = *(const bf16x8*)(vg + (size_t)strow * S + stcol);
  bf16x8 pv1 = *(const bf16x8*)(vg + (size_t)strow * S + stcol + 8);

  // quantum: cumprod(cos(q)) for 128 rows; 4 threads/row, 2 passes
  {
    float c[2][16];
    const int ss = tid & 3;
#pragma unroll
    for (int pass = 0; pass < 2; ++pass) {
      const int rr = pass * 64 + (tid >> 2);
      const bf16_t* qr = qg + rr * 64 + ss * 16;
      float p = 1.f;
#pragma unroll
      for (int j2 = 0; j2 < 16; ++j2) {
        c[pass][j2] = __cosf((float)qr[j2]);
        p *= c[pass][j2];
      }
      segp[rr][ss] = p;
    }
    __syncthreads();
#pragma unroll
    for (int pass = 0; pass < 2; ++pass) {
      const int rr = pass * 64 + (tid >> 2);
      float pre = 1.f;
      for (int u = 0; u < ss; ++u) pre *= segp[rr][u];
#pragma unroll
      for (int j2 = 0; j2 < 16; ++j2) {
        pre *= c[pass][j2];
        Ql[rr * LDK + ss * 16 + j2] = (bf16_t)pre;
      }
    }
  }

  // Q fragments (B-operand of S^T = K Q^T), pre-scaled by 0.125*log2(e)
  // so that exp(q.k/8) = exp2(mfma result).
  bf16x8 aq[2][2];
#pragma unroll
  for (int qs = 0; qs < 2; ++qs) {
    const int qrow = w * 32 + qs * 16 + tc;
#pragma unroll
    for (int ks = 0; ks < 2; ++ks) {
      bf16x8 t = *(const bf16x8*)(qg + qrow * 64 + ks * 32 + quad * 8);
#pragma unroll
      for (int e = 0; e < 8; ++e) t[e] = (bf16_t)((float)t[e] * 0.18033688f);
      aq[qs][ks] = t;
    }
  }

  float lacc[2] = {0.f, 0.f};
  f32x4 o[2][4] = {};
  bf16_t* Pw = Ps[w];

  for (int kt = 0; kt < S; kt += 64) {
    __syncthreads();  // WAR on Ks/Vs
    *(bf16x8*)&Ks[strow * LDK + stcol] = pk0;
    *(bf16x8*)&Ks[strow * LDK + stcol + 8] = pk1;
    *(bf16x8*)&Vs[strow * LDK + stcol] = pv0;
    *(bf16x8*)&Vs[strow * LDK + stcol + 8] = pv1;
    if (kt + 64 < S) {
      const int nk = kt + 64;
      pk0 = *(const bf16x8*)(kg + (size_t)(nk + strow) * 64 + stcol);
      pk1 = *(const bf16x8*)(kg + (size_t)(nk + strow) * 64 + stcol + 8);
      pv0 = *(const bf16x8*)(vg + (size_t)strow * S + nk + stcol);
      pv1 = *(const bf16x8*)(vg + (size_t)strow * S + nk + stcol + 8);
    }
    __syncthreads();

    // S^T tiles for both q-subtiles; Ks reads shared
    f32x4 sf[2][4] = {};
#pragma unroll
    for (int ks = 0; ks < 2; ++ks) {
#pragma unroll
      for (int nt = 0; nt < 4; ++nt) {
        bf16x8 ak = *(const bf16x8*)&Ks[(nt * 16 + tc) * LDK + ks * 32 + quad * 8];
        sf[0][nt] = __builtin_amdgcn_mfma_f32_16x16x32_bf16(ak, aq[0][ks], sf[0][nt], 0, 0, 0);
        sf[1][nt] = __builtin_amdgcn_mfma_f32_16x16x32_bf16(ak, aq[1][ks], sf[1][nt], 0, 0, 0);
      }
    }

    // p = exp2(s') = exp(q.k/8); keys contiguous per lane -> b64 writes
#pragma unroll
    for (int qs = 0; qs < 2; ++qs) {
#pragma unroll
      for (int nt = 0; nt < 4; ++nt) {
        u16x4 pk;
        float ps = 0.f;
#pragma unroll
        for (int r = 0; r < 4; ++r) {
          const float p = __builtin_amdgcn_exp2f(sf[qs][nt][r]);
          ps += p;
          pk[r] = bf16_bits(p);
        }
        lacc[qs] += ps;
        *(u16x4*)&Pw[(qs * 16 + tc) * LDK + nt * 16 + quad * 4] = pk;
      }
    }
    asm volatile("s_waitcnt lgkmcnt(0)" ::: "memory");

    // O += P V ; Vs reads shared across subtiles
#pragma unroll
    for (int ks = 0; ks < 2; ++ks) {
      bf16x8 ap0 = *(const bf16x8*)&Pw[tc * LDK + ks * 32 + quad * 8];
      bf16x8 ap1 = *(const bf16x8*)&Pw[(16 + tc) * LDK + ks * 32 + quad * 8];
#pragma unroll
      for (int j = 0; j < 4; ++j) {
        bf16x8 bv = *(const bf16x8*)&Vs[(j * 16 + tc) * LDK + ks * 32 + quad * 8];
        o[0][j] = __builtin_amdgcn_mfma_f32_16x16x32_bf16(ap0, bv, o[0][j], 0, 0, 0);
        o[1][j] = __builtin_amdgcn_mfma_f32_16x16x32_bf16(ap1, bv, o[1][j], 0, 0, 0);
      }
    }
  }

#pragma unroll
  for (int qs = 0; qs < 2; ++qs) {
    lacc[qs] += __shfl_xor(lacc[qs], 16, 64);
    lacc[qs] += __shfl_xor(lacc[qs], 32, 64);
  }

  const float wsig = 1.f / (1.f + __expf(-aqw[0]));
  const int b = bh >> 4, h = bh & 15;
#pragma unroll
  for (int qs = 0; qs < 2; ++qs) {
#pragma unroll
    for (int r = 0; r < 4; ++r) {
      const int lr = quad * 4 + r;
      const float linv = 1.f / __shfl(lacc[qs], lr, 64);
      const int lrow = w * 32 + qs * 16 + lr;
      const int sg = q0 + lrow;
#pragma unroll
      for (int j = 0; j < 4; ++j) {
        const int d = j * 16 + tc;
        const float cl = o[qs][j][r] * linv;
        const float qv = (float)Ql[lrow * LDK + d];
        out[((size_t)(b * 2048 + sg)) * 1024 + h * 64 + d] =
            (bf16_t)(wsig * qv + (1.f - wsig) * cl);
      }
    }
  }
}

// ---------------------------------------------------------------------------
// LN1 + cumprod-scan fused: one block per row.
// ---------------------------------------------------------------------------
__global__ __launch_bounds__(256) void ln1scan_kernel(
    const float* __restrict__ res, const float* __restrict__ g,
    const float* __restrict__ bta, bf16_t* __restrict__ x1,
    bf16_t* __restrict__ q2) {
  const int row = blockIdx.x;
  const int tid = threadIdx.x, w = tid >> 6, lane = tid & 63;
  f32x4 v = *(const f32x4*)&res[(size_t)row * 1024 + tid * 4];
  float s = v[0] + v[1] + v[2] + v[3];
  float sq = v[0] * v[0] + v[1] * v[1] + v[2] * v[2] + v[3] * v[3];
#pragma unroll
  for (int off = 32; off >= 1; off >>= 1) {
    s += __shfl_xor(s, off, 64);
    sq += __shfl_xor(sq, off, 64);
  }
  __shared__ float rs[4], rq[4], wtot[4];
  if (lane == 0) {
    rs[w] = s;
    rq[w] = sq;
  }
  __syncthreads();
  s = rs[0] + rs[1] + rs[2] + rs[3];
  sq = rq[0] + rq[1] + rq[2] + rq[3];
  const float mean = s * (1.f / 1024.f);
  const float var = fmaxf(sq * (1.f / 1024.f) - mean * mean, 0.f);
  const float rstd = rsqrtf(var + 1e-5f);

  const f32x4 gv = *(const f32x4*)&g[tid * 4];
  const f32x4 bv = *(const f32x4*)&bta[tid * 4];
  float c[4], p = 1.f;
  u16x4 xb;
#pragma unroll
  for (int i = 0; i < 4; ++i) {
    const float y = (v[i] - mean) * rstd * gv[i] + bv[i];
    const bf16_t yb = (bf16_t)y;
    xb[i] = __builtin_bit_cast(unsigned short, yb);
    c[i] = __cosf((float)yb);
    p *= c[i];
  }
  *(u16x4*)&x1[(size_t)row * 1024 + tid * 4] = xb;

  float ip = p;
#pragma unroll
  for (int off = 1; off < 64; off <<= 1) {
    const float t = __shfl_up(ip, off, 64);
    if (lane >= off) ip *= t;
  }
  if (lane == 63) wtot[w] = ip;
  __syncthreads();
  float carry = 1.f;
  for (int u = 0; u < w; ++u) carry *= wtot[u];
  float run = __shfl_up(ip, 1, 64);
  if (lane == 0) run = 1.f;
  run *= carry;
  u16x4 qv;
#pragma unroll
  for (int i = 0; i < 4; ++i) {
    run *= c[i];
    qv[i] = bf16_bits(run);
  }
  *(u16x4*)&q2[(size_t)row * 1024 + tid * 4] = qv;
}

// ---------------------------------------------------------------------------
// LN2: f32 in, f32 out
// ---------------------------------------------------------------------------
__global__ __launch_bounds__(256) void ln2_kernel(
    const float* __restrict__ res, const float* __restrict__ g,
    const float* __restrict__ bta, float* __restrict__ out) {
  const int row = blockIdx.x;
  const int tid = threadIdx.x, w = tid >> 6, lane = tid & 63;
  f32x4 v = *(const f32x4*)&res[(size_t)row * 1024 + tid * 4];
  float s = v[0] + v[1] + v[2] + v[3];
  float sq = v[0] * v[0] + v[1] * v[1] + v[2] * v[2] + v[3] * v[3];
#pragma unroll
  for (int off = 32; off >= 1; off >>= 1) {
    s += __shfl_xor(s, off, 64);
    sq += __shfl_xor(sq, off, 64);
  }
  __shared__ float rs[4], rq[4];
  if (lane == 0) {
    rs[w] = s;
    rq[w] = sq;
  }
  __syncthreads();
  s = rs[0] + rs[1] + rs[2] + rs[3];
  sq = rq[0] + rq[1] + rq[2] + rq[3];
  const float mean = s * (1.f / 1024.f);
  const float var = fmaxf(sq * (1.f / 1024.f) - mean * mean, 0.f);
  const float rstd = rsqrtf(var + 1e-5f);
  const f32x4 gv = *(const f32x4*)&g[tid * 4];
  const f32x4 bv = *(const f32x4*)&bta[tid * 4];
  f32x4 y;
#pragma unroll
  for (int i = 0; i < 4; ++i) y[i] = (v[i] - mean) * rstd * gv[i] + bv[i];
  *(f32x4*)&out[(size_t)row * 1024 + tid * 4] = y;
}

// ---------------------------------------------------------------------------
extern "C" void kernel_launch(void* const* d_in, const int* in_sizes, int n_in,
                              void* d_out, int out_size, void* d_ws,
                              size_t ws_size, hipStream_t stream) {
  (void)in_sizes;
  (void)n_in;
  (void)out_size;
  (void)ws_size;
  const float* x = (const float*)d_in[0];
  const float* wq = (const float*)d_in[2];
  const float* wk = (const float*)d_in[3];
  const float* wv = (const float*)d_in[4];
  const float* wo = (const float*)d_in[5];
  const float* attn_qw = (const float*)d_in[7];
  const float* w1 = (const float*)d_in[8];
  const float* b1 = (const float*)d_in[9];
  const float* w2 = (const float*)d_in[10];
  const float* b2 = (const float*)d_in[11];
  const float* ffn_qw = (const float*)d_in[13];
  const float* ln1_g = (const float*)d_in[14];
  const float* ln1_b = (const float*)d_in[15];
  const float* ln2_g = (const float*)d_in[16];
  const float* ln2_b = (const float*)d_in[17];

  char* ws = (char*)d_ws;
  char* wsout = (char*)d_out;
  // ws (<=30 MB):
  bf16_t* wT3 = (bf16_t*)(ws + 0);            // [0,6M)  wo|w1|w2 T (persists)
  bf16_t* wqkvT = (bf16_t*)(ws + 6 * MB);     // [6,12M)  dies after QKVVT
  bf16_t* xc = (bf16_t*)(ws + 12 * MB);       // [12,20M) dies after QKVVT
  bf16_t* qb = (bf16_t*)(ws + 20 * MB);       // [20,28M) dies after attn
  bf16_t* aout = (bf16_t*)(ws + 6 * MB);      // [6,14M)  after attn
  float* res = (float*)(ws + 14 * MB);        // [14,30M) after WO
  bf16_t* x1 = (bf16_t*)(ws + 6 * MB);        // [6,14M)  after LN1 (aout dead)
  float* res2 = (float*)(ws + 14 * MB);       // [14,30M)
  // d_out (16 MB) as scratch:
  bf16_t* kb = (bf16_t*)(wsout + 0);          // [0,8M)   dies after attn
  bf16_t* vTb = (bf16_t*)(wsout + 8 * MB);    // [8,16M)  dies after attn
  bf16_t* q2 = (bf16_t*)(wsout + 0);          // [0,8M)   after attn
  bf16_t* hbuf = (bf16_t*)(wsout + 8 * MB);   // [8,16M)  after attn

  const dim3 tb(256);

  prep_kernel<<<8192, tb, 0, stream>>>(x, wq, wk, wv, wo, w1, w2, xc, wqkvT, wT3);

  qkvvt_kernel<<<768, tb, 0, stream>>>(xc, wqkvT, qb, kb, vTb);

  attn_kernel<<<dim3(16, 32), tb, 0, stream>>>(qb, kb, vTb, attn_qw, aout);

  gemm_bt_kernel<EPI_WO><<<dim3(16, 64), tb, 0, stream>>>(
      aout, wT3, res, x, nullptr, nullptr, nullptr);

  ln1scan_kernel<<<4096, tb, 0, stream>>>(res, ln1_g, ln1_b, x1, q2);

  gemm_bt_kernel<EPI_W1><<<dim3(16, 64), tb, 0, stream>>>(
      x1, wT3 + 1024 * 1024, hbuf, nullptr, q2, b1, ffn_qw);

  gemm_bt_kernel<EPI_W2><<<dim3(16, 64), tb, 0, stream>>>(
      hbuf, wT3 + 2 * 1024 * 1024, res2, nullptr, x1, b2, nullptr);

  ln2_kernel<<<4096, tb, 0, stream>>>(res2, ln2_g, ln2_b, (float*)d_out);
}